// Round 11
// baseline (202.557 us; speedup 1.0000x reference)
//
#include <hip/hip_runtime.h>
#include <hip/hip_bf16.h>
#include <math.h>

#define NNODES 10000
#define NT     80000
#define NE     1280000
#define NBKT   625       // coarse buckets = NT/128
#define CHUNK  5000      // edges per A-block = NE/256
#define BNEPS  1e-5f

typedef __bf16 bf16x8 __attribute__((ext_vector_type(8)));
typedef float  f32x4  __attribute__((ext_vector_type(4)));
typedef float  f32x2  __attribute__((ext_vector_type(2)));

__device__ __forceinline__ float frcp(float x){ return __builtin_amdgcn_rcpf(x); }
__device__ __forceinline__ float fsig(float x){ return frcp(1.0f + __expf(-x)); }
__device__ __forceinline__ float ftanh(float x){ return 1.0f - 2.0f*frcp(1.0f + __expf(2.0f*x)); }
__device__ __forceinline__ float u2f(unsigned int u){ union{unsigned int u; float f;} c; c.u=u; return c.f; }
__device__ __forceinline__ unsigned int f2u(float f){ union{float f; unsigned int u;} c; c.f=f; return c.u; }
__device__ __forceinline__ unsigned short f2bu(float v){ __hip_bfloat16 h = __float2bfloat16(v); return *(unsigned short*)&h; }
__device__ __forceinline__ unsigned int pk2(float a, float b){ return (unsigned int)f2bu(a) | ((unsigned int)f2bu(b) << 16); }
// 15-bit float decode: 8-bit exp, 6-bit mantissa, positive only
__device__ __forceinline__ float dec15(unsigned int p){ return u2f((p & 0x7fffu) << 17); }

// ---------------- weight prep ------------------------------------------------
__global__ __launch_bounds__(256) void prep_w_kernel(
    const float* __restrict__ wih1, const float* __restrict__ whh1,
    const float* __restrict__ bih1, const float* __restrict__ bhh1,
    const float* __restrict__ wih2, const float* __restrict__ whh2,
    const float* __restrict__ bih2, const float* __restrict__ bhh2,
    const float* __restrict__ w1g, const float* __restrict__ w2g,
    unsigned int* __restrict__ W1f, unsigned int* __restrict__ W2f,
    float* __restrict__ bs1, float* __restrict__ bs2,
    unsigned int* __restrict__ W2g, unsigned int* __restrict__ W1g)
{
    int gid = blockIdx.x*256 + threadIdx.x;
    if (gid < 24576) {
        int i = gid & 3, lane = (gid>>2)&63, rest = gid>>8;
        int ks = rest % 6; rest /= 6;
        int nt = rest & 3, w = rest >> 2;
        int gate = nt*64 + w*16 + (lane & 15);
        int k = ks*32 + ((lane>>4)&3)*8 + 2*i;
        float v0 = (k     < 128) ? wih1[gate*128 + k]       : whh1[gate*64 + (k-128)];
        float v1 = (k + 1 < 128) ? wih1[gate*128 + k + 1]   : whh1[gate*64 + (k+1-128)];
        W1f[gid] = pk2(v0, v1);
    } else if (gid < 40960) {
        int r = gid - 24576;
        int i = r & 3, lane = (r>>2)&63, rest = r>>8;
        int ks = rest & 3; rest >>= 2;
        int nt = rest & 3, w = rest >> 2;
        int gate = nt*64 + w*16 + (lane & 15);
        int k = ks*32 + ((lane>>4)&3)*8 + 2*i;
        float v0 = (k     < 64) ? wih2[gate*64 + k]     : whh2[gate*64 + (k-64)];
        float v1 = (k + 1 < 64) ? wih2[gate*64 + k + 1] : whh2[gate*64 + (k+1-64)];
        W2f[r] = pk2(v0, v1);
    } else if (gid < 41216) {
        int j = gid - 40960; bs1[j] = bih1[j] + bhh1[j];
    } else if (gid < 41472) {
        int j = gid - 41216; bs2[j] = bih2[j] + bhh2[j];
    } else if (gid < 43520) {
        int r = gid - 41472;
        int i = r & 3, lane = (r>>2)&63, rest = r>>8;
        int ks = rest & 1, w = rest >> 1;
        int col = w*16 + (lane & 15);
        int k = ks*32 + ((lane>>4)&3)*8 + 2*i;
        W2g[r] = pk2(w2g[k*64 + col], w2g[(k+1)*64 + col]);
    } else if (gid < 44544) {
        int r = gid - 43520;
        int i = r & 3, lane = (r>>2)&63, w = r>>8;
        int col = w*16 + (lane & 15);
        int k = ((lane>>4)&3)*8 + 2*i;
        float v0 = (k     < 8) ? w1g[k*64 + col]     : 0.f;
        float v1 = (k + 1 < 8) ? w1g[(k+1)*64 + col] : 0.f;
        W1g[r] = pk2(v0, v1);
    }
}

// ---------- deterministic two-level counting sort (no global atomics) --------
__global__ __launch_bounds__(256) void sortA1_kernel(const int* __restrict__ dst,
                                                     int* __restrict__ histmat)
{
    __shared__ int h[NBKT];
    for (int i = threadIdx.x; i < NBKT; i += 256) h[i] = 0;
    __syncthreads();
    int base = blockIdx.x*CHUNK;
    for (int i = threadIdx.x; i < CHUNK; i += 256)
        atomicAdd(&h[dst[base + i] >> 7], 1);
    __syncthreads();
    for (int i = threadIdx.x; i < NBKT; i += 256)
        histmat[blockIdx.x*640 + i] = h[i];
}

__global__ __launch_bounds__(256) void sortA2a_kernel(const int* __restrict__ histmat,
                                                      int* __restrict__ offmatT,
                                                      int* __restrict__ binTotal)
{
    __shared__ int v[256];
    int b = blockIdx.x, t = threadIdx.x;
    int x = histmat[t*640 + b];
    v[t] = x;
    __syncthreads();
    for (int off = 1; off < 256; off <<= 1) {
        int y = (t >= off) ? v[t-off] : 0;
        __syncthreads();
        v[t] += y;
        __syncthreads();
    }
    offmatT[b*256 + t] = v[t] - x;
    if (t == 255) binTotal[b] = v[255];
}

__global__ __launch_bounds__(1024) void sortA2b_kernel(const int* __restrict__ binTotal,
                                                       int* __restrict__ bucketbase,
                                                       int* __restrict__ rowptr)
{
    __shared__ int part[1024];
    int t = threadIdx.x;
    int v = (t < NBKT) ? binTotal[t] : 0;
    part[t] = v;
    __syncthreads();
    for (int off = 1; off < 1024; off <<= 1) {
        int y = (t >= off) ? part[t-off] : 0;
        __syncthreads();
        part[t] += y;
        __syncthreads();
    }
    if (t < NBKT) bucketbase[t] = part[t] - v;
    if (t == 0) { bucketbase[NBKT] = NE; rowptr[NT] = NE; }
}

__global__ __launch_bounds__(256) void sortA3_kernel(const int* __restrict__ src,
                                                     const int* __restrict__ dst,
                                                     const float* __restrict__ ew,
                                                     const int* __restrict__ offmatT,
                                                     const int* __restrict__ bucketbase,
                                                     uint2* __restrict__ esort)
{
    __shared__ int cur[NBKT];
    int blk = blockIdx.x;
    for (int i = threadIdx.x; i < NBKT; i += 256)
        cur[i] = bucketbase[i] + offmatT[i*256 + blk];
    __syncthreads();
    int base = blk*CHUNK;
    for (int i = threadIdx.x; i < CHUNK; i += 256) {
        int e = base + i;
        int d = dst[e];
        int pos = atomicAdd(&cur[d >> 7], 1);
        uint2 r;
        r.x = (unsigned int)src[e] | ((unsigned int)(d & 127) << 17);
        r.y = f2u(ew[e]);
        esort[pos] = r;
    }
}

__global__ __launch_bounds__(256) void sortB1_kernel(const int* __restrict__ bucketbase,
                                                     const uint2* __restrict__ esort,
                                                     unsigned char* __restrict__ urank,
                                                     int* __restrict__ rowptr,
                                                     float* __restrict__ dinv)
{
    __shared__ int cnt[128];
    __shared__ float dg[128];
    __shared__ int ptr[128];
    int bin = blockIdx.x, t = threadIdx.x;
    if (t < 128) { cnt[t] = 0; dg[t] = 0.f; }
    __syncthreads();
    int base = bucketbase[bin], end = bucketbase[bin+1];
    for (int i = base + t; i < end; i += 256) {
        uint2 r = esort[i];
        int dl = (r.x >> 17) & 127;
        int rk = atomicAdd(&cnt[dl], 1);
        atomicAdd(&dg[dl], u2f(r.y));
        urank[i] = (unsigned char)rk;
    }
    __syncthreads();
    if (t < 128) ptr[t] = cnt[t];
    __syncthreads();
    for (int off = 1; off < 128; off <<= 1) {
        int y = (t >= off && t < 128) ? ptr[t-off] : 0;
        __syncthreads();
        if (t < 128) ptr[t] += y;
        __syncthreads();
    }
    if (t < 128) {
        rowptr[bin*128 + t] = base + ptr[t] - cnt[t];
        dinv[bin*128 + t]   = rsqrtf(dg[t] + 1.0f);
    }
}

__global__ __launch_bounds__(256) void sortB2_kernel(const int* __restrict__ bucketbase,
                                                     const uint2* __restrict__ esort,
                                                     const unsigned char* __restrict__ urank,
                                                     const int* __restrict__ rowptr,
                                                     const float* __restrict__ dinv,
                                                     unsigned int* __restrict__ epack)
{
    int bin = blockIdx.x;
    int base = bucketbase[bin], end = bucketbase[bin+1];
    for (int i = base + threadIdx.x; i < end; i += 256) {
        uint2 r = esort[i];
        int s = r.x & 0x1FFFF;
        int d = bin*128 + ((r.x >> 17) & 127);
        float w = u2f(r.y) * dinv[s];
        unsigned int p15 = (f2u(w) + (1u << 16)) >> 17;
        epack[rowptr[d] + (int)urank[i]] = ((unsigned int)s << 15) | p15;
    }
}

// X f32 [NT,8] -> Xb bf16 (packed dwords, 4 per row)
__global__ __launch_bounds__(256) void xconv_kernel(const float* __restrict__ X,
                                                    unsigned int* __restrict__ Xb)
{
    int gid = blockIdx.x*256 + threadIdx.x;
    if (gid >= NT*4) return;
    float2 v = *(const float2*)&X[(size_t)gid*2];
    Xb[gid] = pk2(v.x, v.y);
}

// thread-per-dst 8-channel aggregation; dinv[d] folded; OUTPUT bf16 (uint4/row)
__global__ __launch_bounds__(256) void gather8_kernel(const int* __restrict__ rowptr,
                                                      const unsigned int* __restrict__ epack,
                                                      const uint4* __restrict__ Xb,
                                                      const float* __restrict__ dinv,
                                                      uint4* __restrict__ agg8b)
{
    int d = blockIdx.x*256 + threadIdx.x;
    if (d >= NT) return;
    int beg = rowptr[d], end = rowptr[d+1];
    float acc[8];
    #pragma unroll
    for (int k = 0; k < 8; ++k) acc[k] = 0.f;
    for (int i = beg; i < end; ++i) {
        unsigned int p = epack[i];
        float nrm = dec15(p);
        uint4 xv = Xb[p >> 15];
        unsigned int um[4] = {xv.x, xv.y, xv.z, xv.w};
        #pragma unroll
        for (int m = 0; m < 4; ++m) {
            acc[2*m]   = fmaf(nrm, u2f(um[m] << 16),         acc[2*m]);
            acc[2*m+1] = fmaf(nrm, u2f(um[m] & 0xffff0000u), acc[2*m+1]);
        }
    }
    float dv = dinv[d];
    uint4 xd = Xb[d];
    unsigned int ud[4] = {xd.x, xd.y, xd.z, xd.w};
    #pragma unroll
    for (int m = 0; m < 4; ++m) {
        acc[2*m]   = dv * fmaf(dv, u2f(ud[m] << 16),         acc[2*m]);
        acc[2*m+1] = dv * fmaf(dv, u2f(ud[m] & 0xffff0000u), acc[2*m+1]);
    }
    agg8b[d] = make_uint4(pk2(acc[0],acc[1]), pk2(acc[2],acc[3]),
                          pk2(acc[4],acc[5]), pk2(acc[6],acc[7]));
}

// y1 = relu(agg8b @ w1 + b1) via MFMA -> bf16 (pre-BN); fused BN stats.
__global__ __launch_bounds__(256) void gemm8relu_kernel(const uint4* __restrict__ agg8b,
                                                        const unsigned int* __restrict__ W1g,
                                                        const float* __restrict__ b,
                                                        unsigned short* __restrict__ y,
                                                        float* __restrict__ sums)
{
    __shared__ __align__(16) unsigned short As[64][8];
    __shared__ float sm[256], sq[256];
    const int tid = threadIdx.x;
    const int w = tid >> 6, lane = tid & 63, lr = lane & 15, lg = lane >> 4;
    union { uint4 u; bf16x8 v; } bw; bw.u = ((const uint4*)W1g)[w*64 + lane];
    float bc = b[w*16 + lr];
    float s = 0.f, q = 0.f;
    for (int tile = blockIdx.x; tile < NT/64; tile += gridDim.x) {
        int rbase = tile*64;
        __syncthreads();
        if (tid < 64) *(uint4*)&As[tid][0] = agg8b[rbase + tid];
        __syncthreads();
        #pragma unroll
        for (int rt = 0; rt < 4; ++rt) {
            bf16x8 a = {};
            if (lg == 0) a = *(const bf16x8*)&As[rt*16 + lr][0];
            f32x4 acc = {0.f, 0.f, 0.f, 0.f};
            acc = __builtin_amdgcn_mfma_f32_16x16x32_bf16(a, bw.v, acc, 0, 0, 0);
            #pragma unroll
            for (int r = 0; r < 4; ++r) {
                float v = fmaxf(acc[r] + bc, 0.f);
                y[(size_t)(rbase + rt*16 + lg*4 + r)*64 + w*16 + lr] = f2bu(v);
                s += v; q += v*v;
            }
        }
    }
    sm[tid] = s; sq[tid] = q;
    __syncthreads();
    if (tid < 64) {
        int base = (tid >> 4)*64 + (tid & 15);
        atomicAdd(&sums[tid],      sm[base] + sm[base+16] + sm[base+32] + sm[base+48]);
        atomicAdd(&sums[64 + tid], sq[base] + sq[base+16] + sq[base+32] + sq[base+48]);
    }
}

// BN apply once: y1 (pre-BN bf16) -> BN'd x1 bf16 into xcat[0:32]
//                               -> BN'd x1 fp8 e4m3 table x8 [NT][64]
__global__ __launch_bounds__(256) void xbn8_kernel(const unsigned int* __restrict__ y1,
                                                   const float* __restrict__ sums,
                                                   const float* __restrict__ g,
                                                   const float* __restrict__ be,
                                                   unsigned int* __restrict__ xcat,
                                                   unsigned int* __restrict__ x8)
{
    __shared__ float axs[64], bxs[64];
    int tid = threadIdx.x;
    if (tid < 64) {
        float mu  = sums[tid] * (1.0f/NT);
        float var = sums[64 + tid] * (1.0f/NT) - mu*mu;
        float a = rsqrtf(var + BNEPS) * g[tid];
        axs[tid] = a; bxs[tid] = be[tid] - mu*a;
    }
    __syncthreads();
    int gid = blockIdx.x*256 + tid;            // over NT*16 channel-quads
    if (gid >= NT*16) return;
    int c4 = gid & 15, n = gid >> 4;
    int c0 = c4*4;
    uint2 yy = *(const uint2*)&y1[(size_t)n*32 + 2*c4];
    float v0 = fmaf(axs[c0+0], u2f(yy.x << 16),         bxs[c0+0]);
    float v1 = fmaf(axs[c0+1], u2f(yy.x & 0xffff0000u), bxs[c0+1]);
    float v2 = fmaf(axs[c0+2], u2f(yy.y << 16),         bxs[c0+2]);
    float v3 = fmaf(axs[c0+3], u2f(yy.y & 0xffff0000u), bxs[c0+3]);
    *(uint2*)&xcat[(size_t)n*64 + 2*c4] = make_uint2(pk2(v0, v1), pk2(v2, v3));
    int p8 = 0;
    p8 = __builtin_amdgcn_cvt_pk_fp8_f32(v0, v1, p8, false);
    p8 = __builtin_amdgcn_cvt_pk_fp8_f32(v2, v3, p8, true);
    x8[(size_t)n*16 + c4] = (unsigned int)p8;
}

// 64-ch gather from fp8 table (64 B/row): 4 edges/wave, lane = 1 dword = 4 ch.
// Self-loop from BN'd bf16 xcat[0:32]; aggregate (bf16) -> xcat[32:64].
__global__ __launch_bounds__(256) void gather64_kernel(const int* __restrict__ rowptr,
                                                       const unsigned int* __restrict__ epack,
                                                       const unsigned int* __restrict__ x8,
                                                       const float* __restrict__ dinv,
                                                       unsigned int* __restrict__ xcat)
{
    int lane = threadIdx.x & 63;
    int grp = lane >> 4, l = lane & 15;       // edge slot, channel quad
    int gwave = blockIdx.x*4 + (threadIdx.x >> 6);
    int nwaves = gridDim.x*4;
    for (int d = gwave; d < NT; d += nwaves) {
        int beg = rowptr[d], end = rowptr[d+1];
        float a0 = 0.f, a1 = 0.f, a2 = 0.f, a3 = 0.f;
        for (int i = beg; i < end; i += 4) {
            int idx = i + grp;
            bool valid = idx < end;
            unsigned int p = epack[valid ? idx : (end - 1)];
            float nrm = valid ? dec15(p) : 0.f;
            unsigned int xv = x8[(size_t)(p >> 15)*16 + l];
            f32x2 lo = __builtin_amdgcn_cvt_pk_f32_fp8((int)xv, false);
            f32x2 hi = __builtin_amdgcn_cvt_pk_f32_fp8((int)xv, true);
            a0 = fmaf(nrm, lo[0], a0);
            a1 = fmaf(nrm, lo[1], a1);
            a2 = fmaf(nrm, hi[0], a2);
            a3 = fmaf(nrm, hi[1], a3);
        }
        a0 += __shfl_xor(a0, 16); a1 += __shfl_xor(a1, 16);
        a2 += __shfl_xor(a2, 16); a3 += __shfl_xor(a3, 16);
        a0 += __shfl_xor(a0, 32); a1 += __shfl_xor(a1, 32);
        a2 += __shfl_xor(a2, 32); a3 += __shfl_xor(a3, 32);
        if (grp == 0) {
            float dv = dinv[d];
            uint2 xd = *(const uint2*)&xcat[(size_t)d*64 + 2*l];  // BN'd x1 bf16
            float x0 = u2f(xd.x << 16), x1 = u2f(xd.x & 0xffff0000u);
            float x2 = u2f(xd.y << 16), x3 = u2f(xd.y & 0xffff0000u);
            a0 = dv * fmaf(dv, x0, a0);
            a1 = dv * fmaf(dv, x1, a1);
            a2 = dv * fmaf(dv, x2, a2);
            a3 = dv * fmaf(dv, x3, a3);
            *(uint2*)&xcat[(size_t)d*64 + 32 + 2*l] = make_uint2(pk2(a0, a1), pk2(a2, a3));
        }
    }
}

// y2 = relu(agg2 @ w2 + b2) via MFMA -> bf16 (pre-BN); fused BN stats.
__global__ __launch_bounds__(256) void gemm64relu_kernel(const unsigned int* __restrict__ xcat,
                                                         const unsigned int* __restrict__ W2g,
                                                         const float* __restrict__ b,
                                                         unsigned short* __restrict__ y,
                                                         float* __restrict__ sums)
{
    __shared__ __align__(16) unsigned short As[64][72];
    __shared__ float sm[256], sq[256];
    const int tid = threadIdx.x;
    const int w = tid >> 6, lane = tid & 63, lr = lane & 15, lg = lane >> 4;
    union { uint4 u; bf16x8 v; } b0, b1;
    b0.u = ((const uint4*)W2g)[(w*2 + 0)*64 + lane];
    b1.u = ((const uint4*)W2g)[(w*2 + 1)*64 + lane];
    float bc = b[w*16 + lr];
    const int srow = tid >> 2, squad = tid & 3;
    float s = 0.f, q = 0.f;
    for (int tile = blockIdx.x; tile < NT/64; tile += gridDim.x) {
        int rbase = tile*64;
        __syncthreads();
        {
            const unsigned int* src = &xcat[(size_t)(rbase + srow)*64 + 32 + squad*8];
            unsigned int* dst = (unsigned int*)&As[srow][0] + squad*8;
            *(uint4*)(dst)     = *(const uint4*)(src);
            *(uint4*)(dst + 4) = *(const uint4*)(src + 4);
        }
        __syncthreads();
        #pragma unroll
        for (int rt = 0; rt < 4; ++rt) {
            bf16x8 a0 = *(const bf16x8*)&As[rt*16 + lr][lg*8];
            bf16x8 a1 = *(const bf16x8*)&As[rt*16 + lr][32 + lg*8];
            f32x4 acc = {0.f, 0.f, 0.f, 0.f};
            acc = __builtin_amdgcn_mfma_f32_16x16x32_bf16(a0, b0.v, acc, 0, 0, 0);
            acc = __builtin_amdgcn_mfma_f32_16x16x32_bf16(a1, b1.v, acc, 0, 0, 0);
            #pragma unroll
            for (int r = 0; r < 4; ++r) {
                float v = fmaxf(acc[r] + bc, 0.f);
                y[(size_t)(rbase + rt*16 + lg*4 + r)*64 + w*16 + lr] = f2bu(v);
                s += v; q += v*v;
            }
        }
    }
    sm[tid] = s; sq[tid] = q;
    __syncthreads();
    if (tid < 64) {
        int base = (tid >> 4)*64 + (tid & 15);
        atomicAdd(&sums[tid],      sm[base] + sm[base+16] + sm[base+32] + sm[base+48]);
        atomicAdd(&sums[64 + tid], sq[base] + sq[base+16] + sq[base+32] + sq[base+48]);
    }
}

// ---------------- fused 2-layer 8-step LSTM on MFMA (3 barriers/step) --------
#define LROW 328
__global__ __launch_bounds__(256, 2) void lstm_mfma_kernel(
    const unsigned int* __restrict__ xcat,
    const unsigned int* __restrict__ y2,
    const float* __restrict__ sums2, const float* __restrict__ g2,
    const float* __restrict__ be2,
    const unsigned int* __restrict__ W1f, const unsigned int* __restrict__ W2f,
    const float* __restrict__ bs1, const float* __restrict__ bs2,
    float* __restrict__ out)
{
    __shared__ __align__(16) unsigned short xb[16][LROW];
    const int tid  = threadIdx.x;
    const int w    = tid >> 6, lane = tid & 63;
    const int lr   = lane & 15;
    const int lg   = lane >> 4;
    const int nb0  = blockIdx.x * 16;

    uint4 w1f[4][6], w2f[4][4];
    {
        const uint4* p1 = (const uint4*)W1f;
        #pragma unroll
        for (int nt = 0; nt < 4; ++nt)
            #pragma unroll
            for (int ks = 0; ks < 6; ++ks)
                w1f[nt][ks] = p1[((w*4 + nt)*6 + ks)*64 + lane];
        const uint4* p2 = (const uint4*)W2f;
        #pragma unroll
        for (int nt = 0; nt < 4; ++nt)
            #pragma unroll
            for (int ks = 0; ks < 4; ++ks)
                w2f[nt][ks] = p2[((w*4 + nt)*4 + ks)*64 + lane];
    }
    float b1v[4], b2v[4];
    #pragma unroll
    for (int nt = 0; nt < 4; ++nt) {
        b1v[nt] = bs1[nt*64 + w*16 + lr];
        b2v[nt] = bs2[nt*64 + w*16 + lr];
    }

    const int sn = tid >> 4, k0 = (tid & 15)*8;
    float ax[8], bx[8];
    if (k0 >= 64) {
        #pragma unroll
        for (int j = 0; j < 8; ++j) {
            int c = k0 - 64 + j;
            float mu  = sums2[c] * (1.0f/NT);
            float var = sums2[64 + c] * (1.0f/NT) - mu*mu;
            float a = rsqrtf(var + BNEPS) * g2[c];
            ax[j] = a; bx[j] = be2[c] - mu*a;
        }
    }

    for (int i = tid; i < 16*24; i += 256) {
        int n = i / 24, kk = 128 + (i % 24)*8;
        uint4 z; z.x = z.y = z.z = z.w = 0u;
        *(uint4*)&xb[n][kk] = z;
    }

    auto stage = [&](int step) {
        size_t row = (size_t)(step*NNODES + nb0 + sn);
        uint4 raw;
        if (k0 < 64) {
            raw = *(const uint4*)&xcat[row*64 + (k0 >> 1)];
        } else {
            raw = *(const uint4*)&y2[row*32 + ((k0 - 64) >> 1)];
            unsigned int um[4] = {raw.x, raw.y, raw.z, raw.w};
            #pragma unroll
            for (int m = 0; m < 4; ++m) {
                float v0 = fmaf(ax[2*m],   u2f(um[m] << 16),         bx[2*m]);
                float v1 = fmaf(ax[2*m+1], u2f(um[m] & 0xffff0000u), bx[2*m+1]);
                um[m] = pk2(v0, v1);
            }
            raw.x = um[0]; raw.y = um[1]; raw.z = um[2]; raw.w = um[3];
        }
        *(uint4*)&xb[sn][k0] = raw;
    };
    stage(0);
    float c1[4] = {0.f,0.f,0.f,0.f}, c2[4] = {0.f,0.f,0.f,0.f};

    for (int step = 0; step < 8; ++step) {
        __syncthreads();                    // B_a

        f32x4 acc[4];
        #pragma unroll
        for (int nt = 0; nt < 4; ++nt) { acc[nt][0]=0.f; acc[nt][1]=0.f; acc[nt][2]=0.f; acc[nt][3]=0.f; }
        #pragma unroll
        for (int ks = 0; ks < 6; ++ks) {
            bf16x8 a = *(const bf16x8*)&xb[lr][ks*32 + lg*8];
            #pragma unroll
            for (int nt = 0; nt < 4; ++nt) {
                union { uint4 u; bf16x8 v; } wb; wb.u = w1f[nt][ks];
                acc[nt] = __builtin_amdgcn_mfma_f32_16x16x32_bf16(a, wb.v, acc[nt], 0, 0, 0);
            }
        }
        __syncthreads();                    // B_b

        #pragma unroll
        for (int r = 0; r < 4; ++r) {
            float zi = acc[0][r] + b1v[0];
            float zf = acc[1][r] + b1v[1];
            float zg = acc[2][r] + b1v[2];
            float zo = acc[3][r] + b1v[3];
            float c  = fsig(zf)*c1[r] + fsig(zi)*ftanh(zg);
            c1[r] = c;
            float hv = fsig(zo)*ftanh(c);
            int node = lg*4 + r;
            xb[node][128 + w*16 + lr] = f2bu(hv);
            if (step == 7) out[(size_t)(nb0 + node)*143 + w*16 + lr] = hv;
        }
        if (step < 7) stage(step + 1);
        __syncthreads();                    // B_c

        int rb = 192 + 64*((step+1)&1);
        int wb2 = 192 + 64*(step&1);
        #pragma unroll
        for (int nt = 0; nt < 4; ++nt) { acc[nt][0]=0.f; acc[nt][1]=0.f; acc[nt][2]=0.f; acc[nt][3]=0.f; }
        #pragma unroll
        for (int ks = 0; ks < 2; ++ks) {
            bf16x8 a = *(const bf16x8*)&xb[lr][128 + ks*32 + lg*8];
            #pragma unroll
            for (int nt = 0; nt < 4; ++nt) {
                union { uint4 u; bf16x8 v; } wbv; wbv.u = w2f[nt][ks];
                acc[nt] = __builtin_amdgcn_mfma_f32_16x16x32_bf16(a, wbv.v, acc[nt], 0, 0, 0);
            }
        }
        #pragma unroll
        for (int ks = 0; ks < 2; ++ks) {
            bf16x8 a = *(const bf16x8*)&xb[lr][rb + ks*32 + lg*8];
            #pragma unroll
            for (int nt = 0; nt < 4; ++nt) {
                union { uint4 u; bf16x8 v; } wbv; wbv.u = w2f[nt][2+ks];
                acc[nt] = __builtin_amdgcn_mfma_f32_16x16x32_bf16(a, wbv.v, acc[nt], 0, 0, 0);
            }
        }
        #pragma unroll
        for (int r = 0; r < 4; ++r) {
            float zi = acc[0][r] + b2v[0];
            float zf = acc[1][r] + b2v[1];
            float zg = acc[2][r] + b2v[2];
            float zo = acc[3][r] + b2v[3];
            float c  = fsig(zf)*c2[r] + fsig(zi)*ftanh(zg);
            c2[r] = c;
            float hv = fsig(zo)*ftanh(c);
            int node = lg*4 + r;
            xb[node][wb2 + w*16 + lr] = f2bu(hv);
            if (step == 7) out[(size_t)(nb0 + node)*143 + 64 + w*16 + lr] = hv;
        }
    }
}

__global__ __launch_bounds__(256) void sfeat_kernel(const float* __restrict__ X,
                                                    float* __restrict__ out)
{
    int gid = blockIdx.x*256 + threadIdx.x;
    if (gid >= NNODES*15) return;
    int n = gid/15, i = gid%15;
    float v = (i < 8) ? X[(size_t)n*8 + i]
                      : X[((size_t)(i-7)*NNODES + n)*8 + 7];
    out[(size_t)n*143 + 128 + i] = v;
}

extern "C" void kernel_launch(void* const* d_in, const int* in_sizes, int n_in,
                              void* d_out, int out_size, void* d_ws, size_t ws_size,
                              hipStream_t stream)
{
    (void)in_sizes; (void)n_in; (void)out_size; (void)ws_size;
    const float* X    = (const float*)d_in[0];
    const int*   ei   = (const int*)d_in[1];
    const float* ew   = (const float*)d_in[2];
    const float* w1   = (const float*)d_in[3];
    const float* b1   = (const float*)d_in[4];
    const float* w2   = (const float*)d_in[5];
    const float* b2   = (const float*)d_in[6];
    const float* g1   = (const float*)d_in[7];
    const float* be1  = (const float*)d_in[8];
    const float* g2   = (const float*)d_in[9];
    const float* be2  = (const float*)d_in[10];
    const float* wih1 = (const float*)d_in[11];
    const float* whh1 = (const float*)d_in[12];
    const float* bih1 = (const float*)d_in[13];
    const float* bhh1 = (const float*)d_in[14];
    const float* wih2 = (const float*)d_in[15];
    const float* whh2 = (const float*)d_in[16];
    const float* bih2 = (const float*)d_in[17];
    const float* bhh2 = (const float*)d_in[18];
    float* out = (float*)d_out;
    float* ws  = (float*)d_ws;

    const int* src = ei;
    const int* dst = ei + NE;

    // workspace layout (word offsets)
    float* sums      = ws;                                //  256 [zeroed]
    float* dinv      = ws + 256;                          //  NT
    int*   rowptr    = (int*)(ws + 80256);                //  NT+1 (pad 4)
    int*   binTotal  = (int*)(ws + 160260);               //  625 (pad 640)
    int*   bucketbase= (int*)(ws + 160900);               //  626 (pad 640)
    int*   histmat   = (int*)(ws + 161540);               //  256*640
    int*   offmatT   = (int*)(ws + 325380);               //  625*256
    unsigned char* urank = (unsigned char*)(ws + 485380); //  NE bytes
    uint2* esort     = (uint2*)(ws + 805384);             //  NE*2 w
    unsigned int* x8 = (unsigned int*)(ws + 805384);      //  NT*16 w (alias: esort dead by then)
    unsigned int* y2 = (unsigned int*)(ws + 805384);      //  NT*32 w (alias: x8 dead by then)
    unsigned int* epack = (unsigned int*)(ws + 3365384);  //  NE w
    unsigned int* Xb = (unsigned int*)(ws + 4645384);     //  NT*4
    uint4* agg8b     = (uint4*)(ws + 4965384);            //  NT*4 w (bf16 rows)
    unsigned int* y1 = (unsigned int*)(ws + 5605384);     //  NT*32
    unsigned int* xcat = (unsigned int*)(ws + 8165384);   //  NT*64
    unsigned int* W1f  = (unsigned int*)(ws + 13285384);  //  24576
    unsigned int* W2f  = W1f + 24576;                     //  16384
    float* bs1 = (float*)(W2f + 16384);                   //  256
    float* bs2 = bs1 + 256;                               //  256
    unsigned int* W2g  = (unsigned int*)(bs2 + 256);      //  2048
    unsigned int* W1g  = W2g + 2048;                      //  1024

    hipMemsetAsync(ws, 0, 256 * 4, stream);

    prep_w_kernel<<<174, 256, 0, stream>>>(wih1,whh1,bih1,bhh1,
                                           wih2,whh2,bih2,bhh2,
                                           w1, w2,
                                           W1f,W2f,bs1,bs2,W2g,W1g);
    // deterministic two-level counting sort (no global atomics)
    sortA1_kernel<<<256, 256, 0, stream>>>(dst, histmat);
    sortA2a_kernel<<<NBKT, 256, 0, stream>>>(histmat, offmatT, binTotal);
    sortA2b_kernel<<<1, 1024, 0, stream>>>(binTotal, bucketbase, rowptr);
    sortA3_kernel<<<256, 256, 0, stream>>>(src, dst, ew, offmatT, bucketbase, esort);
    sortB1_kernel<<<NBKT, 256, 0, stream>>>(bucketbase, esort, urank, rowptr, dinv);
    sortB2_kernel<<<NBKT, 256, 0, stream>>>(bucketbase, esort, urank, rowptr, dinv, epack);
    xconv_kernel<<<(NT*4+255)/256, 256, 0, stream>>>(X, Xb);

    // GCN layer 1
    gather8_kernel<<<(NT+255)/256, 256, 0, stream>>>(rowptr, epack, (const uint4*)Xb, dinv, agg8b);
    gemm8relu_kernel<<<320, 256, 0, stream>>>(agg8b, W1g, b1, (unsigned short*)y1, sums);

    // BN apply -> bf16 x1 (xcat[0:32]) + fp8 gather table x8
    xbn8_kernel<<<(NT*16+255)/256, 256, 0, stream>>>(y1, sums, g1, be1, xcat, x8);

    // GCN layer 2: fp8 gather, MFMA GEMM (BN2 fused into LSTM staging)
    gather64_kernel<<<2048, 256, 0, stream>>>(rowptr, epack, x8, dinv, xcat);
    gemm64relu_kernel<<<320, 256, 0, stream>>>(xcat, W2g, b2, (unsigned short*)y2, sums + 128);

    // fused MFMA LSTM + skip features
    lstm_mfma_kernel<<<NNODES/16, 256, 0, stream>>>(xcat, y2, sums + 128, g2, be2,
                                                    W1f, W2f, bs1, bs2, out);
    sfeat_kernel<<<(NNODES*15+255)/256, 256, 0, stream>>>(X, out);
}

// Round 12
// 192.562 us; speedup vs baseline: 1.0519x; 1.0519x over previous
//
#include <hip/hip_runtime.h>
#include <hip/hip_bf16.h>
#include <math.h>

#define NNODES 10000
#define NT     80000
#define NE     1280000
#define NBKT   625       // coarse buckets = NT/128
#define CHUNK  5000      // edges per A-block = NE/256
#define BNEPS  1e-5f

typedef __bf16 bf16x8 __attribute__((ext_vector_type(8)));
typedef float  f32x4  __attribute__((ext_vector_type(4)));
typedef float  f32x2  __attribute__((ext_vector_type(2)));

__device__ __forceinline__ float frcp(float x){ return __builtin_amdgcn_rcpf(x); }
__device__ __forceinline__ float fsig(float x){ return frcp(1.0f + __expf(-x)); }
__device__ __forceinline__ float ftanh(float x){ return 1.0f - 2.0f*frcp(1.0f + __expf(2.0f*x)); }
__device__ __forceinline__ float u2f(unsigned int u){ union{unsigned int u; float f;} c; c.u=u; return c.f; }
__device__ __forceinline__ unsigned int f2u(float f){ union{float f; unsigned int u;} c; c.f=f; return c.u; }
__device__ __forceinline__ unsigned short f2bu(float v){ __hip_bfloat16 h = __float2bfloat16(v); return *(unsigned short*)&h; }
__device__ __forceinline__ unsigned int pk2(float a, float b){ return (unsigned int)f2bu(a) | ((unsigned int)f2bu(b) << 16); }
// 15-bit float decode: 8-bit exp, 6-bit mantissa, positive only
__device__ __forceinline__ float dec15(unsigned int p){ return u2f((p & 0x7fffu) << 17); }

// ---------------- weight prep ------------------------------------------------
__global__ __launch_bounds__(256) void prep_w_kernel(
    const float* __restrict__ wih1, const float* __restrict__ whh1,
    const float* __restrict__ bih1, const float* __restrict__ bhh1,
    const float* __restrict__ wih2, const float* __restrict__ whh2,
    const float* __restrict__ bih2, const float* __restrict__ bhh2,
    const float* __restrict__ w1g, const float* __restrict__ w2g,
    unsigned int* __restrict__ W1f, unsigned int* __restrict__ W2f,
    float* __restrict__ bs1, float* __restrict__ bs2,
    unsigned int* __restrict__ W2g, unsigned int* __restrict__ W1g)
{
    int gid = blockIdx.x*256 + threadIdx.x;
    if (gid < 24576) {
        int i = gid & 3, lane = (gid>>2)&63, rest = gid>>8;
        int ks = rest % 6; rest /= 6;
        int nt = rest & 3, w = rest >> 2;
        int gate = nt*64 + w*16 + (lane & 15);
        int k = ks*32 + ((lane>>4)&3)*8 + 2*i;
        float v0 = (k     < 128) ? wih1[gate*128 + k]       : whh1[gate*64 + (k-128)];
        float v1 = (k + 1 < 128) ? wih1[gate*128 + k + 1]   : whh1[gate*64 + (k+1-128)];
        W1f[gid] = pk2(v0, v1);
    } else if (gid < 40960) {
        int r = gid - 24576;
        int i = r & 3, lane = (r>>2)&63, rest = r>>8;
        int ks = rest & 3; rest >>= 2;
        int nt = rest & 3, w = rest >> 2;
        int gate = nt*64 + w*16 + (lane & 15);
        int k = ks*32 + ((lane>>4)&3)*8 + 2*i;
        float v0 = (k     < 64) ? wih2[gate*64 + k]     : whh2[gate*64 + (k-64)];
        float v1 = (k + 1 < 64) ? wih2[gate*64 + k + 1] : whh2[gate*64 + (k+1-64)];
        W2f[r] = pk2(v0, v1);
    } else if (gid < 41216) {
        int j = gid - 40960; bs1[j] = bih1[j] + bhh1[j];
    } else if (gid < 41472) {
        int j = gid - 41216; bs2[j] = bih2[j] + bhh2[j];
    } else if (gid < 43520) {
        int r = gid - 41472;
        int i = r & 3, lane = (r>>2)&63, rest = r>>8;
        int ks = rest & 1, w = rest >> 1;
        int col = w*16 + (lane & 15);
        int k = ks*32 + ((lane>>4)&3)*8 + 2*i;
        W2g[r] = pk2(w2g[k*64 + col], w2g[(k+1)*64 + col]);
    } else if (gid < 44544) {
        int r = gid - 43520;
        int i = r & 3, lane = (r>>2)&63, w = r>>8;
        int col = w*16 + (lane & 15);
        int k = ((lane>>4)&3)*8 + 2*i;
        float v0 = (k     < 8) ? w1g[k*64 + col]     : 0.f;
        float v1 = (k + 1 < 8) ? w1g[(k+1)*64 + col] : 0.f;
        W1g[r] = pk2(v0, v1);
    }
}

// ---------- deterministic two-level counting sort (no global atomics) --------
__global__ __launch_bounds__(256) void sortA1_kernel(const int* __restrict__ dst,
                                                     int* __restrict__ histmat)
{
    __shared__ int h[NBKT];
    for (int i = threadIdx.x; i < NBKT; i += 256) h[i] = 0;
    __syncthreads();
    int base = blockIdx.x*CHUNK;
    for (int i = threadIdx.x; i < CHUNK; i += 256)
        atomicAdd(&h[dst[base + i] >> 7], 1);
    __syncthreads();
    for (int i = threadIdx.x; i < NBKT; i += 256)
        histmat[blockIdx.x*640 + i] = h[i];
}

__global__ __launch_bounds__(256) void sortA2a_kernel(const int* __restrict__ histmat,
                                                      int* __restrict__ offmatT,
                                                      int* __restrict__ binTotal)
{
    __shared__ int v[256];
    int b = blockIdx.x, t = threadIdx.x;
    int x = histmat[t*640 + b];
    v[t] = x;
    __syncthreads();
    for (int off = 1; off < 256; off <<= 1) {
        int y = (t >= off) ? v[t-off] : 0;
        __syncthreads();
        v[t] += y;
        __syncthreads();
    }
    offmatT[b*256 + t] = v[t] - x;
    if (t == 255) binTotal[b] = v[255];
}

__global__ __launch_bounds__(1024) void sortA2b_kernel(const int* __restrict__ binTotal,
                                                       int* __restrict__ bucketbase,
                                                       int* __restrict__ rowptr)
{
    __shared__ int part[1024];
    int t = threadIdx.x;
    int v = (t < NBKT) ? binTotal[t] : 0;
    part[t] = v;
    __syncthreads();
    for (int off = 1; off < 1024; off <<= 1) {
        int y = (t >= off) ? part[t-off] : 0;
        __syncthreads();
        part[t] += y;
        __syncthreads();
    }
    if (t < NBKT) bucketbase[t] = part[t] - v;
    if (t == 0) { bucketbase[NBKT] = NE; rowptr[NT] = NE; }
}

__global__ __launch_bounds__(256) void sortA3_kernel(const int* __restrict__ src,
                                                     const int* __restrict__ dst,
                                                     const float* __restrict__ ew,
                                                     const int* __restrict__ offmatT,
                                                     const int* __restrict__ bucketbase,
                                                     uint2* __restrict__ esort)
{
    __shared__ int cur[NBKT];
    int blk = blockIdx.x;
    for (int i = threadIdx.x; i < NBKT; i += 256)
        cur[i] = bucketbase[i] + offmatT[i*256 + blk];
    __syncthreads();
    int base = blk*CHUNK;
    for (int i = threadIdx.x; i < CHUNK; i += 256) {
        int e = base + i;
        int d = dst[e];
        int pos = atomicAdd(&cur[d >> 7], 1);
        uint2 r;
        r.x = (unsigned int)src[e] | ((unsigned int)(d & 127) << 17);
        r.y = f2u(ew[e]);
        esort[pos] = r;
    }
}

__global__ __launch_bounds__(256) void sortB1_kernel(const int* __restrict__ bucketbase,
                                                     const uint2* __restrict__ esort,
                                                     unsigned char* __restrict__ urank,
                                                     int* __restrict__ rowptr,
                                                     float* __restrict__ dinv)
{
    __shared__ int cnt[128];
    __shared__ float dg[128];
    __shared__ int ptr[128];
    int bin = blockIdx.x, t = threadIdx.x;
    if (t < 128) { cnt[t] = 0; dg[t] = 0.f; }
    __syncthreads();
    int base = bucketbase[bin], end = bucketbase[bin+1];
    for (int i = base + t; i < end; i += 256) {
        uint2 r = esort[i];
        int dl = (r.x >> 17) & 127;
        int rk = atomicAdd(&cnt[dl], 1);
        atomicAdd(&dg[dl], u2f(r.y));
        urank[i] = (unsigned char)rk;
    }
    __syncthreads();
    if (t < 128) ptr[t] = cnt[t];
    __syncthreads();
    for (int off = 1; off < 128; off <<= 1) {
        int y = (t >= off && t < 128) ? ptr[t-off] : 0;
        __syncthreads();
        if (t < 128) ptr[t] += y;
        __syncthreads();
    }
    if (t < 128) {
        rowptr[bin*128 + t] = base + ptr[t] - cnt[t];
        dinv[bin*128 + t]   = rsqrtf(dg[t] + 1.0f);
    }
}

__global__ __launch_bounds__(256) void sortB2_kernel(const int* __restrict__ bucketbase,
                                                     const uint2* __restrict__ esort,
                                                     const unsigned char* __restrict__ urank,
                                                     const int* __restrict__ rowptr,
                                                     const float* __restrict__ dinv,
                                                     unsigned int* __restrict__ epack)
{
    int bin = blockIdx.x;
    int base = bucketbase[bin], end = bucketbase[bin+1];
    for (int i = base + threadIdx.x; i < end; i += 256) {
        uint2 r = esort[i];
        int s = r.x & 0x1FFFF;
        int d = bin*128 + ((r.x >> 17) & 127);
        float w = u2f(r.y) * dinv[s];
        unsigned int p15 = (f2u(w) + (1u << 16)) >> 17;
        epack[rowptr[d] + (int)urank[i]] = ((unsigned int)s << 15) | p15;
    }
}

// X f32 [NT,8] -> Xb bf16 (packed dwords, 4 per row)
__global__ __launch_bounds__(256) void xconv_kernel(const float* __restrict__ X,
                                                    unsigned int* __restrict__ Xb)
{
    int gid = blockIdx.x*256 + threadIdx.x;
    if (gid >= NT*4) return;
    float2 v = *(const float2*)&X[(size_t)gid*2];
    Xb[gid] = pk2(v.x, v.y);
}

// thread-per-dst 8-channel aggregation; dinv[d] folded; OUTPUT bf16 (uint4/row)
__global__ __launch_bounds__(256) void gather8_kernel(const int* __restrict__ rowptr,
                                                      const unsigned int* __restrict__ epack,
                                                      const uint4* __restrict__ Xb,
                                                      const float* __restrict__ dinv,
                                                      uint4* __restrict__ agg8b)
{
    int d = blockIdx.x*256 + threadIdx.x;
    if (d >= NT) return;
    int beg = rowptr[d], end = rowptr[d+1];
    float acc[8];
    #pragma unroll
    for (int k = 0; k < 8; ++k) acc[k] = 0.f;
    for (int i = beg; i < end; ++i) {
        unsigned int p = epack[i];
        float nrm = dec15(p);
        uint4 xv = Xb[p >> 15];
        unsigned int um[4] = {xv.x, xv.y, xv.z, xv.w};
        #pragma unroll
        for (int m = 0; m < 4; ++m) {
            acc[2*m]   = fmaf(nrm, u2f(um[m] << 16),         acc[2*m]);
            acc[2*m+1] = fmaf(nrm, u2f(um[m] & 0xffff0000u), acc[2*m+1]);
        }
    }
    float dv = dinv[d];
    uint4 xd = Xb[d];
    unsigned int ud[4] = {xd.x, xd.y, xd.z, xd.w};
    #pragma unroll
    for (int m = 0; m < 4; ++m) {
        acc[2*m]   = dv * fmaf(dv, u2f(ud[m] << 16),         acc[2*m]);
        acc[2*m+1] = dv * fmaf(dv, u2f(ud[m] & 0xffff0000u), acc[2*m+1]);
    }
    agg8b[d] = make_uint4(pk2(acc[0],acc[1]), pk2(acc[2],acc[3]),
                          pk2(acc[4],acc[5]), pk2(acc[6],acc[7]));
}

// y1 = relu(agg8b @ w1 + b1) via MFMA -> bf16 (pre-BN); fused BN stats.
__global__ __launch_bounds__(256) void gemm8relu_kernel(const uint4* __restrict__ agg8b,
                                                        const unsigned int* __restrict__ W1g,
                                                        const float* __restrict__ b,
                                                        unsigned short* __restrict__ y,
                                                        float* __restrict__ sums)
{
    __shared__ __align__(16) unsigned short As[64][8];
    __shared__ float sm[256], sq[256];
    const int tid = threadIdx.x;
    const int w = tid >> 6, lane = tid & 63, lr = lane & 15, lg = lane >> 4;
    union { uint4 u; bf16x8 v; } bw; bw.u = ((const uint4*)W1g)[w*64 + lane];
    float bc = b[w*16 + lr];
    float s = 0.f, q = 0.f;
    for (int tile = blockIdx.x; tile < NT/64; tile += gridDim.x) {
        int rbase = tile*64;
        __syncthreads();
        if (tid < 64) *(uint4*)&As[tid][0] = agg8b[rbase + tid];
        __syncthreads();
        #pragma unroll
        for (int rt = 0; rt < 4; ++rt) {
            bf16x8 a = {};
            if (lg == 0) a = *(const bf16x8*)&As[rt*16 + lr][0];
            f32x4 acc = {0.f, 0.f, 0.f, 0.f};
            acc = __builtin_amdgcn_mfma_f32_16x16x32_bf16(a, bw.v, acc, 0, 0, 0);
            #pragma unroll
            for (int r = 0; r < 4; ++r) {
                float v = fmaxf(acc[r] + bc, 0.f);
                y[(size_t)(rbase + rt*16 + lg*4 + r)*64 + w*16 + lr] = f2bu(v);
                s += v; q += v*v;
            }
        }
    }
    sm[tid] = s; sq[tid] = q;
    __syncthreads();
    if (tid < 64) {
        int base = (tid >> 4)*64 + (tid & 15);
        atomicAdd(&sums[tid],      sm[base] + sm[base+16] + sm[base+32] + sm[base+48]);
        atomicAdd(&sums[64 + tid], sq[base] + sq[base+16] + sq[base+32] + sq[base+48]);
    }
}

// BN apply once: y1 (pre-BN bf16) -> BN'd x1 bf16 into xcat[0:32]
//                               -> BN'd x1 fp8 e4m3 table x8 [NT][64]
__global__ __launch_bounds__(256) void xbn8_kernel(const unsigned int* __restrict__ y1,
                                                   const float* __restrict__ sums,
                                                   const float* __restrict__ g,
                                                   const float* __restrict__ be,
                                                   unsigned int* __restrict__ xcat,
                                                   unsigned int* __restrict__ x8)
{
    __shared__ float axs[64], bxs[64];
    int tid = threadIdx.x;
    if (tid < 64) {
        float mu  = sums[tid] * (1.0f/NT);
        float var = sums[64 + tid] * (1.0f/NT) - mu*mu;
        float a = rsqrtf(var + BNEPS) * g[tid];
        axs[tid] = a; bxs[tid] = be[tid] - mu*a;
    }
    __syncthreads();
    int gid = blockIdx.x*256 + tid;            // over NT*16 channel-quads
    if (gid >= NT*16) return;
    int c4 = gid & 15, n = gid >> 4;
    int c0 = c4*4;
    uint2 yy = *(const uint2*)&y1[(size_t)n*32 + 2*c4];
    float v0 = fmaf(axs[c0+0], u2f(yy.x << 16),         bxs[c0+0]);
    float v1 = fmaf(axs[c0+1], u2f(yy.x & 0xffff0000u), bxs[c0+1]);
    float v2 = fmaf(axs[c0+2], u2f(yy.y << 16),         bxs[c0+2]);
    float v3 = fmaf(axs[c0+3], u2f(yy.y & 0xffff0000u), bxs[c0+3]);
    *(uint2*)&xcat[(size_t)n*64 + 2*c4] = make_uint2(pk2(v0, v1), pk2(v2, v3));
    int p8 = 0;
    p8 = __builtin_amdgcn_cvt_pk_fp8_f32(v0, v1, p8, false);
    p8 = __builtin_amdgcn_cvt_pk_fp8_f32(v2, v3, p8, true);
    x8[(size_t)n*16 + c4] = (unsigned int)p8;
}

// 64-ch gather from fp8 table: 8 edges/wave (8-lane groups, uint2 = 8 ch/lane).
// Doubles memory-level parallelism vs 4-edge variant (latency-bound regime).
// Self-loop from BN'd bf16 xcat[0:32]; aggregate (bf16) -> xcat[32:64].
__global__ __launch_bounds__(256) void gather64_kernel(const int* __restrict__ rowptr,
                                                       const unsigned int* __restrict__ epack,
                                                       const unsigned int* __restrict__ x8,
                                                       const float* __restrict__ dinv,
                                                       unsigned int* __restrict__ xcat)
{
    int lane = threadIdx.x & 63;
    int g = lane >> 3;                        // edge slot 0..7
    int l = lane & 7;                         // channel octet (8 ch = 2 dwords fp8)
    int gwave = blockIdx.x*4 + (threadIdx.x >> 6);
    int nwaves = gridDim.x*4;
    for (int d = gwave; d < NT; d += nwaves) {
        int beg = rowptr[d], end = rowptr[d+1];
        float a0=0.f,a1=0.f,a2=0.f,a3=0.f,a4=0.f,a5=0.f,a6=0.f,a7=0.f;
        for (int i = beg; i < end; i += 8) {
            int idx = i + g;
            bool valid = idx < end;
            unsigned int p = epack[valid ? idx : (end - 1)];
            float nrm = valid ? dec15(p) : 0.f;
            uint2 xv = *(const uint2*)&x8[(size_t)(p >> 15)*16 + 2*l];
            f32x2 q0 = __builtin_amdgcn_cvt_pk_f32_fp8((int)xv.x, false);
            f32x2 q1 = __builtin_amdgcn_cvt_pk_f32_fp8((int)xv.x, true);
            f32x2 q2 = __builtin_amdgcn_cvt_pk_f32_fp8((int)xv.y, false);
            f32x2 q3 = __builtin_amdgcn_cvt_pk_f32_fp8((int)xv.y, true);
            a0 = fmaf(nrm, q0[0], a0); a1 = fmaf(nrm, q0[1], a1);
            a2 = fmaf(nrm, q1[0], a2); a3 = fmaf(nrm, q1[1], a3);
            a4 = fmaf(nrm, q2[0], a4); a5 = fmaf(nrm, q2[1], a5);
            a6 = fmaf(nrm, q3[0], a6); a7 = fmaf(nrm, q3[1], a7);
        }
        #pragma unroll
        for (int off = 8; off < 64; off <<= 1) {
            a0 += __shfl_xor(a0, off); a1 += __shfl_xor(a1, off);
            a2 += __shfl_xor(a2, off); a3 += __shfl_xor(a3, off);
            a4 += __shfl_xor(a4, off); a5 += __shfl_xor(a5, off);
            a6 += __shfl_xor(a6, off); a7 += __shfl_xor(a7, off);
        }
        if (g == 0) {
            float dv = dinv[d];
            uint4 xd = *(const uint4*)&xcat[(size_t)d*64 + 4*l];  // BN'd x1 bf16, ch 8l..8l+7
            float x0 = u2f(xd.x << 16), x1 = u2f(xd.x & 0xffff0000u);
            float x2 = u2f(xd.y << 16), x3 = u2f(xd.y & 0xffff0000u);
            float x4 = u2f(xd.z << 16), x5 = u2f(xd.z & 0xffff0000u);
            float x6 = u2f(xd.w << 16), x7 = u2f(xd.w & 0xffff0000u);
            a0 = dv * fmaf(dv, x0, a0); a1 = dv * fmaf(dv, x1, a1);
            a2 = dv * fmaf(dv, x2, a2); a3 = dv * fmaf(dv, x3, a3);
            a4 = dv * fmaf(dv, x4, a4); a5 = dv * fmaf(dv, x5, a5);
            a6 = dv * fmaf(dv, x6, a6); a7 = dv * fmaf(dv, x7, a7);
            *(uint4*)&xcat[(size_t)d*64 + 32 + 4*l] =
                make_uint4(pk2(a0,a1), pk2(a2,a3), pk2(a4,a5), pk2(a6,a7));
        }
    }
}

// y2 = relu(agg2 @ w2 + b2) via MFMA -> bf16 (pre-BN); fused BN stats.
__global__ __launch_bounds__(256) void gemm64relu_kernel(const unsigned int* __restrict__ xcat,
                                                         const unsigned int* __restrict__ W2g,
                                                         const float* __restrict__ b,
                                                         unsigned short* __restrict__ y,
                                                         float* __restrict__ sums)
{
    __shared__ __align__(16) unsigned short As[64][72];
    __shared__ float sm[256], sq[256];
    const int tid = threadIdx.x;
    const int w = tid >> 6, lane = tid & 63, lr = lane & 15, lg = lane >> 4;
    union { uint4 u; bf16x8 v; } b0, b1;
    b0.u = ((const uint4*)W2g)[(w*2 + 0)*64 + lane];
    b1.u = ((const uint4*)W2g)[(w*2 + 1)*64 + lane];
    float bc = b[w*16 + lr];
    const int srow = tid >> 2, squad = tid & 3;
    float s = 0.f, q = 0.f;
    for (int tile = blockIdx.x; tile < NT/64; tile += gridDim.x) {
        int rbase = tile*64;
        __syncthreads();
        {
            const unsigned int* src = &xcat[(size_t)(rbase + srow)*64 + 32 + squad*8];
            unsigned int* dst = (unsigned int*)&As[srow][0] + squad*8;
            *(uint4*)(dst)     = *(const uint4*)(src);
            *(uint4*)(dst + 4) = *(const uint4*)(src + 4);
        }
        __syncthreads();
        #pragma unroll
        for (int rt = 0; rt < 4; ++rt) {
            bf16x8 a0 = *(const bf16x8*)&As[rt*16 + lr][lg*8];
            bf16x8 a1 = *(const bf16x8*)&As[rt*16 + lr][32 + lg*8];
            f32x4 acc = {0.f, 0.f, 0.f, 0.f};
            acc = __builtin_amdgcn_mfma_f32_16x16x32_bf16(a0, b0.v, acc, 0, 0, 0);
            acc = __builtin_amdgcn_mfma_f32_16x16x32_bf16(a1, b1.v, acc, 0, 0, 0);
            #pragma unroll
            for (int r = 0; r < 4; ++r) {
                float v = fmaxf(acc[r] + bc, 0.f);
                y[(size_t)(rbase + rt*16 + lg*4 + r)*64 + w*16 + lr] = f2bu(v);
                s += v; q += v*v;
            }
        }
    }
    sm[tid] = s; sq[tid] = q;
    __syncthreads();
    if (tid < 64) {
        int base = (tid >> 4)*64 + (tid & 15);
        atomicAdd(&sums[tid],      sm[base] + sm[base+16] + sm[base+32] + sm[base+48]);
        atomicAdd(&sums[64 + tid], sq[base] + sq[base+16] + sq[base+32] + sq[base+48]);
    }
}

// ---------------- fused 2-layer 8-step LSTM on MFMA (3 barriers/step) --------
#define LROW 328
__global__ __launch_bounds__(256, 2) void lstm_mfma_kernel(
    const unsigned int* __restrict__ xcat,
    const unsigned int* __restrict__ y2,
    const float* __restrict__ sums2, const float* __restrict__ g2,
    const float* __restrict__ be2,
    const unsigned int* __restrict__ W1f, const unsigned int* __restrict__ W2f,
    const float* __restrict__ bs1, const float* __restrict__ bs2,
    float* __restrict__ out)
{
    __shared__ __align__(16) unsigned short xb[16][LROW];
    const int tid  = threadIdx.x;
    const int w    = tid >> 6, lane = tid & 63;
    const int lr   = lane & 15;
    const int lg   = lane >> 4;
    const int nb0  = blockIdx.x * 16;

    uint4 w1f[4][6], w2f[4][4];
    {
        const uint4* p1 = (const uint4*)W1f;
        #pragma unroll
        for (int nt = 0; nt < 4; ++nt)
            #pragma unroll
            for (int ks = 0; ks < 6; ++ks)
                w1f[nt][ks] = p1[((w*4 + nt)*6 + ks)*64 + lane];
        const uint4* p2 = (const uint4*)W2f;
        #pragma unroll
        for (int nt = 0; nt < 4; ++nt)
            #pragma unroll
            for (int ks = 0; ks < 4; ++ks)
                w2f[nt][ks] = p2[((w*4 + nt)*4 + ks)*64 + lane];
    }
    float b1v[4], b2v[4];
    #pragma unroll
    for (int nt = 0; nt < 4; ++nt) {
        b1v[nt] = bs1[nt*64 + w*16 + lr];
        b2v[nt] = bs2[nt*64 + w*16 + lr];
    }

    const int sn = tid >> 4, k0 = (tid & 15)*8;
    float ax[8], bx[8];
    if (k0 >= 64) {
        #pragma unroll
        for (int j = 0; j < 8; ++j) {
            int c = k0 - 64 + j;
            float mu  = sums2[c] * (1.0f/NT);
            float var = sums2[64 + c] * (1.0f/NT) - mu*mu;
            float a = rsqrtf(var + BNEPS) * g2[c];
            ax[j] = a; bx[j] = be2[c] - mu*a;
        }
    }

    for (int i = tid; i < 16*24; i += 256) {
        int n = i / 24, kk = 128 + (i % 24)*8;
        uint4 z; z.x = z.y = z.z = z.w = 0u;
        *(uint4*)&xb[n][kk] = z;
    }

    auto stage = [&](int step) {
        size_t row = (size_t)(step*NNODES + nb0 + sn);
        uint4 raw;
        if (k0 < 64) {
            raw = *(const uint4*)&xcat[row*64 + (k0 >> 1)];
        } else {
            raw = *(const uint4*)&y2[row*32 + ((k0 - 64) >> 1)];
            unsigned int um[4] = {raw.x, raw.y, raw.z, raw.w};
            #pragma unroll
            for (int m = 0; m < 4; ++m) {
                float v0 = fmaf(ax[2*m],   u2f(um[m] << 16),         bx[2*m]);
                float v1 = fmaf(ax[2*m+1], u2f(um[m] & 0xffff0000u), bx[2*m+1]);
                um[m] = pk2(v0, v1);
            }
            raw.x = um[0]; raw.y = um[1]; raw.z = um[2]; raw.w = um[3];
        }
        *(uint4*)&xb[sn][k0] = raw;
    };
    stage(0);
    float c1[4] = {0.f,0.f,0.f,0.f}, c2[4] = {0.f,0.f,0.f,0.f};

    for (int step = 0; step < 8; ++step) {
        __syncthreads();                    // B_a

        f32x4 acc[4];
        #pragma unroll
        for (int nt = 0; nt < 4; ++nt) { acc[nt][0]=0.f; acc[nt][1]=0.f; acc[nt][2]=0.f; acc[nt][3]=0.f; }
        #pragma unroll
        for (int ks = 0; ks < 6; ++ks) {
            bf16x8 a = *(const bf16x8*)&xb[lr][ks*32 + lg*8];
            #pragma unroll
            for (int nt = 0; nt < 4; ++nt) {
                union { uint4 u; bf16x8 v; } wb; wb.u = w1f[nt][ks];
                acc[nt] = __builtin_amdgcn_mfma_f32_16x16x32_bf16(a, wb.v, acc[nt], 0, 0, 0);
            }
        }
        __syncthreads();                    // B_b

        #pragma unroll
        for (int r = 0; r < 4; ++r) {
            float zi = acc[0][r] + b1v[0];
            float zf = acc[1][r] + b1v[1];
            float zg = acc[2][r] + b1v[2];
            float zo = acc[3][r] + b1v[3];
            float c  = fsig(zf)*c1[r] + fsig(zi)*ftanh(zg);
            c1[r] = c;
            float hv = fsig(zo)*ftanh(c);
            int node = lg*4 + r;
            xb[node][128 + w*16 + lr] = f2bu(hv);
            if (step == 7) out[(size_t)(nb0 + node)*143 + w*16 + lr] = hv;
        }
        if (step < 7) stage(step + 1);
        __syncthreads();                    // B_c

        int rb = 192 + 64*((step+1)&1);
        int wb2 = 192 + 64*(step&1);
        #pragma unroll
        for (int nt = 0; nt < 4; ++nt) { acc[nt][0]=0.f; acc[nt][1]=0.f; acc[nt][2]=0.f; acc[nt][3]=0.f; }
        #pragma unroll
        for (int ks = 0; ks < 2; ++ks) {
            bf16x8 a = *(const bf16x8*)&xb[lr][128 + ks*32 + lg*8];
            #pragma unroll
            for (int nt = 0; nt < 4; ++nt) {
                union { uint4 u; bf16x8 v; } wbv; wbv.u = w2f[nt][ks];
                acc[nt] = __builtin_amdgcn_mfma_f32_16x16x32_bf16(a, wbv.v, acc[nt], 0, 0, 0);
            }
        }
        #pragma unroll
        for (int ks = 0; ks < 2; ++ks) {
            bf16x8 a = *(const bf16x8*)&xb[lr][rb + ks*32 + lg*8];
            #pragma unroll
            for (int nt = 0; nt < 4; ++nt) {
                union { uint4 u; bf16x8 v; } wbv; wbv.u = w2f[nt][2+ks];
                acc[nt] = __builtin_amdgcn_mfma_f32_16x16x32_bf16(a, wbv.v, acc[nt], 0, 0, 0);
            }
        }
        #pragma unroll
        for (int r = 0; r < 4; ++r) {
            float zi = acc[0][r] + b2v[0];
            float zf = acc[1][r] + b2v[1];
            float zg = acc[2][r] + b2v[2];
            float zo = acc[3][r] + b2v[3];
            float c  = fsig(zf)*c2[r] + fsig(zi)*ftanh(zg);
            c2[r] = c;
            float hv = fsig(zo)*ftanh(c);
            int node = lg*4 + r;
            xb[node][wb2 + w*16 + lr] = f2bu(hv);
            if (step == 7) out[(size_t)(nb0 + node)*143 + 64 + w*16 + lr] = hv;
        }
    }
}

__global__ __launch_bounds__(256) void sfeat_kernel(const float* __restrict__ X,
                                                    float* __restrict__ out)
{
    int gid = blockIdx.x*256 + threadIdx.x;
    if (gid >= NNODES*15) return;
    int n = gid/15, i = gid%15;
    float v = (i < 8) ? X[(size_t)n*8 + i]
                      : X[((size_t)(i-7)*NNODES + n)*8 + 7];
    out[(size_t)n*143 + 128 + i] = v;
}

extern "C" void kernel_launch(void* const* d_in, const int* in_sizes, int n_in,
                              void* d_out, int out_size, void* d_ws, size_t ws_size,
                              hipStream_t stream)
{
    (void)in_sizes; (void)n_in; (void)out_size; (void)ws_size;
    const float* X    = (const float*)d_in[0];
    const int*   ei   = (const int*)d_in[1];
    const float* ew   = (const float*)d_in[2];
    const float* w1   = (const float*)d_in[3];
    const float* b1   = (const float*)d_in[4];
    const float* w2   = (const float*)d_in[5];
    const float* b2   = (const float*)d_in[6];
    const float* g1   = (const float*)d_in[7];
    const float* be1  = (const float*)d_in[8];
    const float* g2   = (const float*)d_in[9];
    const float* be2  = (const float*)d_in[10];
    const float* wih1 = (const float*)d_in[11];
    const float* whh1 = (const float*)d_in[12];
    const float* bih1 = (const float*)d_in[13];
    const float* bhh1 = (const float*)d_in[14];
    const float* wih2 = (const float*)d_in[15];
    const float* whh2 = (const float*)d_in[16];
    const float* bih2 = (const float*)d_in[17];
    const float* bhh2 = (const float*)d_in[18];
    float* out = (float*)d_out;
    float* ws  = (float*)d_ws;

    const int* src = ei;
    const int* dst = ei + NE;

    // workspace layout (word offsets)
    float* sums      = ws;                                //  256 [zeroed]
    float* dinv      = ws + 256;                          //  NT
    int*   rowptr    = (int*)(ws + 80256);                //  NT+1 (pad 4)
    int*   binTotal  = (int*)(ws + 160260);               //  625 (pad 640)
    int*   bucketbase= (int*)(ws + 160900);               //  626 (pad 640)
    int*   histmat   = (int*)(ws + 161540);               //  256*640
    int*   offmatT   = (int*)(ws + 325380);               //  625*256
    unsigned char* urank = (unsigned char*)(ws + 485380); //  NE bytes
    uint2* esort     = (uint2*)(ws + 805384);             //  NE*2 w
    unsigned int* x8 = (unsigned int*)(ws + 805384);      //  NT*16 w (alias: esort dead by then)
    unsigned int* y2 = (unsigned int*)(ws + 805384);      //  NT*32 w (alias: x8 dead by then)
    unsigned int* epack = (unsigned int*)(ws + 3365384);  //  NE w
    unsigned int* Xb = (unsigned int*)(ws + 4645384);     //  NT*4
    uint4* agg8b     = (uint4*)(ws + 4965384);            //  NT*4 w (bf16 rows)
    unsigned int* y1 = (unsigned int*)(ws + 5605384);     //  NT*32
    unsigned int* xcat = (unsigned int*)(ws + 8165384);   //  NT*64
    unsigned int* W1f  = (unsigned int*)(ws + 13285384);  //  24576
    unsigned int* W2f  = W1f + 24576;                     //  16384
    float* bs1 = (float*)(W2f + 16384);                   //  256
    float* bs2 = bs1 + 256;                               //  256
    unsigned int* W2g  = (unsigned int*)(bs2 + 256);      //  2048
    unsigned int* W1g  = W2g + 2048;                      //  1024

    hipMemsetAsync(ws, 0, 256 * 4, stream);

    prep_w_kernel<<<174, 256, 0, stream>>>(wih1,whh1,bih1,bhh1,
                                           wih2,whh2,bih2,bhh2,
                                           w1, w2,
                                           W1f,W2f,bs1,bs2,W2g,W1g);
    // deterministic two-level counting sort (no global atomics)
    sortA1_kernel<<<256, 256, 0, stream>>>(dst, histmat);
    sortA2a_kernel<<<NBKT, 256, 0, stream>>>(histmat, offmatT, binTotal);
    sortA2b_kernel<<<1, 1024, 0, stream>>>(binTotal, bucketbase, rowptr);
    sortA3_kernel<<<256, 256, 0, stream>>>(src, dst, ew, offmatT, bucketbase, esort);
    sortB1_kernel<<<NBKT, 256, 0, stream>>>(bucketbase, esort, urank, rowptr, dinv);
    sortB2_kernel<<<NBKT, 256, 0, stream>>>(bucketbase, esort, urank, rowptr, dinv, epack);
    xconv_kernel<<<(NT*4+255)/256, 256, 0, stream>>>(X, Xb);

    // GCN layer 1
    gather8_kernel<<<(NT+255)/256, 256, 0, stream>>>(rowptr, epack, (const uint4*)Xb, dinv, agg8b);
    gemm8relu_kernel<<<320, 256, 0, stream>>>(agg8b, W1g, b1, (unsigned short*)y1, sums);

    // BN apply -> bf16 x1 (xcat[0:32]) + fp8 gather table x8
    xbn8_kernel<<<(NT*16+255)/256, 256, 0, stream>>>(y1, sums, g1, be1, xcat, x8);

    // GCN layer 2: fp8 gather (8-edge MLP), MFMA GEMM (BN2 fused into LSTM staging)
    gather64_kernel<<<2048, 256, 0, stream>>>(rowptr, epack, x8, dinv, xcat);
    gemm64relu_kernel<<<320, 256, 0, stream>>>(xcat, W2g, b2, (unsigned short*)y2, sums + 128);

    // fused MFMA LSTM + skip features
    lstm_mfma_kernel<<<NNODES/16, 256, 0, stream>>>(xcat, y2, sums + 128, g2, be2,
                                                    W1f, W2f, bs1, bs2, out);
    sfeat_kernel<<<(NNODES*15+255)/256, 256, 0, stream>>>(X, out);
}

// Round 13
// 179.723 us; speedup vs baseline: 1.1270x; 1.0714x over previous
//
#include <hip/hip_runtime.h>
#include <hip/hip_bf16.h>
#include <math.h>

#define NNODES 10000
#define NT     80000
#define NE     1280000
#define NBKT   625       // coarse buckets = NT/128
#define CHUNK  5000      // edges per A-block = NE/256
#define EPB    3072      // max edges kept in LDS per bucket (mean 2048, +22 sigma)
#define BNEPS  1e-5f

typedef __bf16 bf16x8 __attribute__((ext_vector_type(8)));
typedef float  f32x4  __attribute__((ext_vector_type(4)));
typedef float  f32x2  __attribute__((ext_vector_type(2)));

__device__ __forceinline__ float frcp(float x){ return __builtin_amdgcn_rcpf(x); }
__device__ __forceinline__ float fsig(float x){ return frcp(1.0f + __expf(-x)); }
__device__ __forceinline__ float ftanh(float x){ return 1.0f - 2.0f*frcp(1.0f + __expf(2.0f*x)); }
__device__ __forceinline__ float u2f(unsigned int u){ union{unsigned int u; float f;} c; c.u=u; return c.f; }
__device__ __forceinline__ unsigned int f2u(float f){ union{float f; unsigned int u;} c; c.f=f; return c.u; }
__device__ __forceinline__ unsigned short f2bu(float v){ __hip_bfloat16 h = __float2bfloat16(v); return *(unsigned short*)&h; }
__device__ __forceinline__ unsigned int pk2(float a, float b){ return (unsigned int)f2bu(a) | ((unsigned int)f2bu(b) << 16); }
// 15-bit float decode: 8-bit exp, 6-bit mantissa, positive only
__device__ __forceinline__ float dec15(unsigned int p){ return u2f((p & 0x7fffu) << 17); }

// ---------------- weight prep ------------------------------------------------
__global__ __launch_bounds__(256) void prep_w_kernel(
    const float* __restrict__ wih1, const float* __restrict__ whh1,
    const float* __restrict__ bih1, const float* __restrict__ bhh1,
    const float* __restrict__ wih2, const float* __restrict__ whh2,
    const float* __restrict__ bih2, const float* __restrict__ bhh2,
    const float* __restrict__ w1g, const float* __restrict__ w2g,
    unsigned int* __restrict__ W1f, unsigned int* __restrict__ W2f,
    float* __restrict__ bs1, float* __restrict__ bs2,
    unsigned int* __restrict__ W2g, unsigned int* __restrict__ W1g)
{
    int gid = blockIdx.x*256 + threadIdx.x;
    if (gid < 24576) {
        int i = gid & 3, lane = (gid>>2)&63, rest = gid>>8;
        int ks = rest % 6; rest /= 6;
        int nt = rest & 3, w = rest >> 2;
        int gate = nt*64 + w*16 + (lane & 15);
        int k = ks*32 + ((lane>>4)&3)*8 + 2*i;
        float v0 = (k     < 128) ? wih1[gate*128 + k]       : whh1[gate*64 + (k-128)];
        float v1 = (k + 1 < 128) ? wih1[gate*128 + k + 1]   : whh1[gate*64 + (k+1-128)];
        W1f[gid] = pk2(v0, v1);
    } else if (gid < 40960) {
        int r = gid - 24576;
        int i = r & 3, lane = (r>>2)&63, rest = r>>8;
        int ks = rest & 3; rest >>= 2;
        int nt = rest & 3, w = rest >> 2;
        int gate = nt*64 + w*16 + (lane & 15);
        int k = ks*32 + ((lane>>4)&3)*8 + 2*i;
        float v0 = (k     < 64) ? wih2[gate*64 + k]     : whh2[gate*64 + (k-64)];
        float v1 = (k + 1 < 64) ? wih2[gate*64 + k + 1] : whh2[gate*64 + (k+1-64)];
        W2f[r] = pk2(v0, v1);
    } else if (gid < 41216) {
        int j = gid - 40960; bs1[j] = bih1[j] + bhh1[j];
    } else if (gid < 41472) {
        int j = gid - 41216; bs2[j] = bih2[j] + bhh2[j];
    } else if (gid < 43520) {
        int r = gid - 41472;
        int i = r & 3, lane = (r>>2)&63, rest = r>>8;
        int ks = rest & 1, w = rest >> 1;
        int col = w*16 + (lane & 15);
        int k = ks*32 + ((lane>>4)&3)*8 + 2*i;
        W2g[r] = pk2(w2g[k*64 + col], w2g[(k+1)*64 + col]);
    } else if (gid < 44544) {
        int r = gid - 43520;
        int i = r & 3, lane = (r>>2)&63, w = r>>8;
        int col = w*16 + (lane & 15);
        int k = ((lane>>4)&3)*8 + 2*i;
        float v0 = (k     < 8) ? w1g[k*64 + col]     : 0.f;
        float v1 = (k + 1 < 8) ? w1g[(k+1)*64 + col] : 0.f;
        W1g[r] = pk2(v0, v1);
    }
}

// ---------- deterministic two-level counting sort (no global atomics) --------
// A1: per-block coarse histogram; also converts X -> Xb bf16 (fused xconv)
__global__ __launch_bounds__(256) void sortA1_kernel(const int* __restrict__ dst,
                                                     const float* __restrict__ X,
                                                     unsigned int* __restrict__ Xb,
                                                     int* __restrict__ histmat)
{
    __shared__ int h[NBKT];
    for (int i = threadIdx.x; i < NBKT; i += 256) h[i] = 0;
    __syncthreads();
    int base = blockIdx.x*CHUNK;
    for (int i = threadIdx.x; i < CHUNK; i += 256)
        atomicAdd(&h[dst[base + i] >> 7], 1);
    // fused xconv: 256 blocks x 1250 dwords = NT*4 exactly
    for (int i = threadIdx.x; i < 1250; i += 256) {
        int gid = blockIdx.x*1250 + i;
        float2 v = *(const float2*)&X[(size_t)gid*2];
        Xb[gid] = pk2(v.x, v.y);
    }
    __syncthreads();
    for (int i = threadIdx.x; i < NBKT; i += 256)
        histmat[blockIdx.x*640 + i] = h[i];
}

__global__ __launch_bounds__(256) void sortA2a_kernel(const int* __restrict__ histmat,
                                                      int* __restrict__ offmatT,
                                                      int* __restrict__ binTotal)
{
    __shared__ int v[256];
    int b = blockIdx.x, t = threadIdx.x;
    int x = histmat[t*640 + b];
    v[t] = x;
    __syncthreads();
    for (int off = 1; off < 256; off <<= 1) {
        int y = (t >= off) ? v[t-off] : 0;
        __syncthreads();
        v[t] += y;
        __syncthreads();
    }
    offmatT[b*256 + t] = v[t] - x;
    if (t == 255) binTotal[b] = v[255];
}

__global__ __launch_bounds__(1024) void sortA2b_kernel(const int* __restrict__ binTotal,
                                                       int* __restrict__ bucketbase,
                                                       int* __restrict__ rowptr)
{
    __shared__ int part[1024];
    int t = threadIdx.x;
    int v = (t < NBKT) ? binTotal[t] : 0;
    part[t] = v;
    __syncthreads();
    for (int off = 1; off < 1024; off <<= 1) {
        int y = (t >= off) ? part[t-off] : 0;
        __syncthreads();
        part[t] += y;
        __syncthreads();
    }
    if (t < NBKT) bucketbase[t] = part[t] - v;
    if (t == 0) { bucketbase[NBKT] = NE; rowptr[NT] = NE; }
}

__global__ __launch_bounds__(256) void sortA3_kernel(const int* __restrict__ src,
                                                     const int* __restrict__ dst,
                                                     const float* __restrict__ ew,
                                                     const int* __restrict__ offmatT,
                                                     const int* __restrict__ bucketbase,
                                                     uint2* __restrict__ esort)
{
    __shared__ int cur[NBKT];
    int blk = blockIdx.x;
    for (int i = threadIdx.x; i < NBKT; i += 256)
        cur[i] = bucketbase[i] + offmatT[i*256 + blk];
    __syncthreads();
    int base = blk*CHUNK;
    for (int i = threadIdx.x; i < CHUNK; i += 256) {
        int e = base + i;
        int d = dst[e];
        int pos = atomicAdd(&cur[d >> 7], 1);
        uint2 r;
        r.x = (unsigned int)src[e] | ((unsigned int)(d & 127) << 17);
        r.y = f2u(ew[e]);
        esort[pos] = r;
    }
}

__global__ __launch_bounds__(256) void sortB1_kernel(const int* __restrict__ bucketbase,
                                                     const uint2* __restrict__ esort,
                                                     unsigned char* __restrict__ urank,
                                                     int* __restrict__ rowptr,
                                                     float* __restrict__ dinv)
{
    __shared__ int cnt[128];
    __shared__ float dg[128];
    __shared__ int ptr[128];
    int bin = blockIdx.x, t = threadIdx.x;
    if (t < 128) { cnt[t] = 0; dg[t] = 0.f; }
    __syncthreads();
    int base = bucketbase[bin], end = bucketbase[bin+1];
    for (int i = base + t; i < end; i += 256) {
        uint2 r = esort[i];
        int dl = (r.x >> 17) & 127;
        int rk = atomicAdd(&cnt[dl], 1);
        atomicAdd(&dg[dl], u2f(r.y));
        urank[i] = (unsigned char)rk;
    }
    __syncthreads();
    if (t < 128) ptr[t] = cnt[t];
    __syncthreads();
    for (int off = 1; off < 128; off <<= 1) {
        int y = (t >= off && t < 128) ? ptr[t-off] : 0;
        __syncthreads();
        if (t < 128) ptr[t] += y;
        __syncthreads();
    }
    if (t < 128) {
        rowptr[bin*128 + t] = base + ptr[t] - cnt[t];
        dinv[bin*128 + t]   = rsqrtf(dg[t] + 1.0f);
    }
}

// B2 fused with layer-1 8-ch gather: build epack (kept in LDS), then
// 2 threads/dst aggregate Xb rows; dinv[d] folded; OUTPUT bf16 agg8b.
__global__ __launch_bounds__(256) void sortB2g8_kernel(const int* __restrict__ bucketbase,
                                                       const uint2* __restrict__ esort,
                                                       const unsigned char* __restrict__ urank,
                                                       const int* __restrict__ rowptr,
                                                       const float* __restrict__ dinv,
                                                       unsigned int* __restrict__ epack,
                                                       const uint4* __restrict__ Xb,
                                                       uint4* __restrict__ agg8b)
{
    __shared__ unsigned int eld[EPB];
    int bin = blockIdx.x;
    int base = bucketbase[bin], end = bucketbase[bin+1];
    int cnt = end - base;
    for (int i = threadIdx.x; i < cnt; i += 256) {
        uint2 r = esort[base + i];
        int s = r.x & 0x1FFFF;
        int d = bin*128 + ((r.x >> 17) & 127);
        float w = u2f(r.y) * dinv[s];
        unsigned int p15 = (f2u(w) + (1u << 16)) >> 17;
        unsigned int pv = ((unsigned int)s << 15) | p15;
        int pos = rowptr[d] + (int)urank[base + i];
        epack[pos] = pv;
        int lpos = pos - base;
        if (lpos < EPB) eld[lpos] = pv;
    }
    __syncthreads();
    int t = threadIdx.x;
    int dl = t >> 1, par = t & 1;
    int d = bin*128 + dl;
    int beg = rowptr[d], endd = rowptr[d+1];
    float acc[8];
    #pragma unroll
    for (int k = 0; k < 8; ++k) acc[k] = 0.f;
    for (int i = beg + par; i < endd; i += 2) {
        int lpos = i - base;
        unsigned int p = (lpos < EPB) ? eld[lpos] : epack[i];
        float nrm = dec15(p);
        uint4 xv = Xb[p >> 15];
        unsigned int um[4] = {xv.x, xv.y, xv.z, xv.w};
        #pragma unroll
        for (int m = 0; m < 4; ++m) {
            acc[2*m]   = fmaf(nrm, u2f(um[m] << 16),         acc[2*m]);
            acc[2*m+1] = fmaf(nrm, u2f(um[m] & 0xffff0000u), acc[2*m+1]);
        }
    }
    #pragma unroll
    for (int k = 0; k < 8; ++k) acc[k] += __shfl_xor(acc[k], 1);
    if (par == 0) {
        float dv = dinv[d];
        uint4 xd = Xb[d];
        unsigned int ud[4] = {xd.x, xd.y, xd.z, xd.w};
        #pragma unroll
        for (int m = 0; m < 4; ++m) {
            acc[2*m]   = dv * fmaf(dv, u2f(ud[m] << 16),         acc[2*m]);
            acc[2*m+1] = dv * fmaf(dv, u2f(ud[m] & 0xffff0000u), acc[2*m+1]);
        }
        agg8b[d] = make_uint4(pk2(acc[0],acc[1]), pk2(acc[2],acc[3]),
                              pk2(acc[4],acc[5]), pk2(acc[6],acc[7]));
    }
}

// y1 = relu(agg8b @ w1 + b1) via MFMA -> bf16 (pre-BN); fused BN stats.
__global__ __launch_bounds__(256) void gemm8relu_kernel(const uint4* __restrict__ agg8b,
                                                        const unsigned int* __restrict__ W1g,
                                                        const float* __restrict__ b,
                                                        unsigned short* __restrict__ y,
                                                        float* __restrict__ sums)
{
    __shared__ __align__(16) unsigned short As[64][8];
    __shared__ float sm[256], sq[256];
    const int tid = threadIdx.x;
    const int w = tid >> 6, lane = tid & 63, lr = lane & 15, lg = lane >> 4;
    union { uint4 u; bf16x8 v; } bw; bw.u = ((const uint4*)W1g)[w*64 + lane];
    float bc = b[w*16 + lr];
    float s = 0.f, q = 0.f;
    for (int tile = blockIdx.x; tile < NT/64; tile += gridDim.x) {
        int rbase = tile*64;
        __syncthreads();
        if (tid < 64) *(uint4*)&As[tid][0] = agg8b[rbase + tid];
        __syncthreads();
        #pragma unroll
        for (int rt = 0; rt < 4; ++rt) {
            bf16x8 a = {};
            if (lg == 0) a = *(const bf16x8*)&As[rt*16 + lr][0];
            f32x4 acc = {0.f, 0.f, 0.f, 0.f};
            acc = __builtin_amdgcn_mfma_f32_16x16x32_bf16(a, bw.v, acc, 0, 0, 0);
            #pragma unroll
            for (int r = 0; r < 4; ++r) {
                float v = fmaxf(acc[r] + bc, 0.f);
                y[(size_t)(rbase + rt*16 + lg*4 + r)*64 + w*16 + lr] = f2bu(v);
                s += v; q += v*v;
            }
        }
    }
    sm[tid] = s; sq[tid] = q;
    __syncthreads();
    if (tid < 64) {
        int base = (tid >> 4)*64 + (tid & 15);
        atomicAdd(&sums[tid],      sm[base] + sm[base+16] + sm[base+32] + sm[base+48]);
        atomicAdd(&sums[64 + tid], sq[base] + sq[base+16] + sq[base+32] + sq[base+48]);
    }
}

// BN apply once: y1 (pre-BN bf16) -> BN'd x1 bf16 into xcat[0:32]
//                               -> BN'd x1 fp8 e4m3 table x8 [NT][64]
__global__ __launch_bounds__(256) void xbn8_kernel(const unsigned int* __restrict__ y1,
                                                   const float* __restrict__ sums,
                                                   const float* __restrict__ g,
                                                   const float* __restrict__ be,
                                                   unsigned int* __restrict__ xcat,
                                                   unsigned int* __restrict__ x8)
{
    __shared__ float axs[64], bxs[64];
    int tid = threadIdx.x;
    if (tid < 64) {
        float mu  = sums[tid] * (1.0f/NT);
        float var = sums[64 + tid] * (1.0f/NT) - mu*mu;
        float a = rsqrtf(var + BNEPS) * g[tid];
        axs[tid] = a; bxs[tid] = be[tid] - mu*a;
    }
    __syncthreads();
    int gid = blockIdx.x*256 + tid;            // over NT*16 channel-quads
    if (gid >= NT*16) return;
    int c4 = gid & 15, n = gid >> 4;
    int c0 = c4*4;
    uint2 yy = *(const uint2*)&y1[(size_t)n*32 + 2*c4];
    float v0 = fmaf(axs[c0+0], u2f(yy.x << 16),         bxs[c0+0]);
    float v1 = fmaf(axs[c0+1], u2f(yy.x & 0xffff0000u), bxs[c0+1]);
    float v2 = fmaf(axs[c0+2], u2f(yy.y << 16),         bxs[c0+2]);
    float v3 = fmaf(axs[c0+3], u2f(yy.y & 0xffff0000u), bxs[c0+3]);
    *(uint2*)&xcat[(size_t)n*64 + 2*c4] = make_uint2(pk2(v0, v1), pk2(v2, v3));
    int p8 = 0;
    p8 = __builtin_amdgcn_cvt_pk_fp8_f32(v0, v1, p8, false);
    p8 = __builtin_amdgcn_cvt_pk_fp8_f32(v2, v3, p8, true);
    x8[(size_t)n*16 + c4] = (unsigned int)p8;
}

// 64-ch gather from fp8 table: 8 edges/wave over TWO dsts concurrently
// (dual independent load chains -> 2x memory-level parallelism at the
// same shuffle-reduce cost). Self-loop from bf16 xcat[0:32];
// aggregate (bf16) -> xcat[32:64].
__global__ __launch_bounds__(256) void gather64_kernel(const int* __restrict__ rowptr,
                                                       const unsigned int* __restrict__ epack,
                                                       const unsigned int* __restrict__ x8,
                                                       const float* __restrict__ dinv,
                                                       unsigned int* __restrict__ xcat)
{
    int lane = threadIdx.x & 63;
    int g = lane >> 3;                        // edge slot 0..7
    int l = lane & 7;                         // channel octet (8 ch = 2 dwords fp8)
    int gwave = blockIdx.x*4 + (threadIdx.x >> 6);
    int nwaves = gridDim.x*4;
    for (int dp = gwave; dp < NT/2; dp += nwaves) {
        int dA = dp*2, dB = dA + 1;
        int begA = rowptr[dA], endA = rowptr[dA+1];
        int begB = endA, endB = rowptr[dB+1];
        int nA = endA - begA, nB = endB - begB;
        int n = nA > nB ? nA : nB;
        int clA = (endA > begA) ? endA - 1 : 0;
        int clB = (endB > begB) ? endB - 1 : 0;
        float a0=0.f,a1=0.f,a2=0.f,a3=0.f,a4=0.f,a5=0.f,a6=0.f,a7=0.f;
        float b0=0.f,b1=0.f,b2=0.f,b3=0.f,b4=0.f,b5=0.f,b6=0.f,b7=0.f;
        for (int i = 0; i < n; i += 8) {
            int iA = begA + i + g;
            bool vA = iA < endA;
            unsigned int pA = epack[vA ? iA : clA];
            float nrmA = vA ? dec15(pA) : 0.f;
            int iB = begB + i + g;
            bool vB = iB < endB;
            unsigned int pB = epack[vB ? iB : clB];
            float nrmB = vB ? dec15(pB) : 0.f;
            uint2 xvA = *(const uint2*)&x8[(size_t)(pA >> 15)*16 + 2*l];
            uint2 xvB = *(const uint2*)&x8[(size_t)(pB >> 15)*16 + 2*l];
            f32x2 qa0 = __builtin_amdgcn_cvt_pk_f32_fp8((int)xvA.x, false);
            f32x2 qa1 = __builtin_amdgcn_cvt_pk_f32_fp8((int)xvA.x, true);
            f32x2 qa2 = __builtin_amdgcn_cvt_pk_f32_fp8((int)xvA.y, false);
            f32x2 qa3 = __builtin_amdgcn_cvt_pk_f32_fp8((int)xvA.y, true);
            a0 = fmaf(nrmA, qa0[0], a0); a1 = fmaf(nrmA, qa0[1], a1);
            a2 = fmaf(nrmA, qa1[0], a2); a3 = fmaf(nrmA, qa1[1], a3);
            a4 = fmaf(nrmA, qa2[0], a4); a5 = fmaf(nrmA, qa2[1], a5);
            a6 = fmaf(nrmA, qa3[0], a6); a7 = fmaf(nrmA, qa3[1], a7);
            f32x2 qb0 = __builtin_amdgcn_cvt_pk_f32_fp8((int)xvB.x, false);
            f32x2 qb1 = __builtin_amdgcn_cvt_pk_f32_fp8((int)xvB.x, true);
            f32x2 qb2 = __builtin_amdgcn_cvt_pk_f32_fp8((int)xvB.y, false);
            f32x2 qb3 = __builtin_amdgcn_cvt_pk_f32_fp8((int)xvB.y, true);
            b0 = fmaf(nrmB, qb0[0], b0); b1 = fmaf(nrmB, qb0[1], b1);
            b2 = fmaf(nrmB, qb1[0], b2); b3 = fmaf(nrmB, qb1[1], b3);
            b4 = fmaf(nrmB, qb2[0], b4); b5 = fmaf(nrmB, qb2[1], b5);
            b6 = fmaf(nrmB, qb3[0], b6); b7 = fmaf(nrmB, qb3[1], b7);
        }
        #pragma unroll
        for (int off = 8; off < 64; off <<= 1) {
            a0 += __shfl_xor(a0, off); a1 += __shfl_xor(a1, off);
            a2 += __shfl_xor(a2, off); a3 += __shfl_xor(a3, off);
            a4 += __shfl_xor(a4, off); a5 += __shfl_xor(a5, off);
            a6 += __shfl_xor(a6, off); a7 += __shfl_xor(a7, off);
            b0 += __shfl_xor(b0, off); b1 += __shfl_xor(b1, off);
            b2 += __shfl_xor(b2, off); b3 += __shfl_xor(b3, off);
            b4 += __shfl_xor(b4, off); b5 += __shfl_xor(b5, off);
            b6 += __shfl_xor(b6, off); b7 += __shfl_xor(b7, off);
        }
        if (g == 0) {
            float dvA = dinv[dA];
            uint4 xdA = *(const uint4*)&xcat[(size_t)dA*64 + 4*l];
            a0 = dvA * fmaf(dvA, u2f(xdA.x << 16),         a0);
            a1 = dvA * fmaf(dvA, u2f(xdA.x & 0xffff0000u), a1);
            a2 = dvA * fmaf(dvA, u2f(xdA.y << 16),         a2);
            a3 = dvA * fmaf(dvA, u2f(xdA.y & 0xffff0000u), a3);
            a4 = dvA * fmaf(dvA, u2f(xdA.z << 16),         a4);
            a5 = dvA * fmaf(dvA, u2f(xdA.z & 0xffff0000u), a5);
            a6 = dvA * fmaf(dvA, u2f(xdA.w << 16),         a6);
            a7 = dvA * fmaf(dvA, u2f(xdA.w & 0xffff0000u), a7);
            *(uint4*)&xcat[(size_t)dA*64 + 32 + 4*l] =
                make_uint4(pk2(a0,a1), pk2(a2,a3), pk2(a4,a5), pk2(a6,a7));
            float dvB = dinv[dB];
            uint4 xdB = *(const uint4*)&xcat[(size_t)dB*64 + 4*l];
            b0 = dvB * fmaf(dvB, u2f(xdB.x << 16),         b0);
            b1 = dvB * fmaf(dvB, u2f(xdB.x & 0xffff0000u), b1);
            b2 = dvB * fmaf(dvB, u2f(xdB.y << 16),         b2);
            b3 = dvB * fmaf(dvB, u2f(xdB.y & 0xffff0000u), b3);
            b4 = dvB * fmaf(dvB, u2f(xdB.z << 16),         b4);
            b5 = dvB * fmaf(dvB, u2f(xdB.z & 0xffff0000u), b5);
            b6 = dvB * fmaf(dvB, u2f(xdB.w << 16),         b6);
            b7 = dvB * fmaf(dvB, u2f(xdB.w & 0xffff0000u), b7);
            *(uint4*)&xcat[(size_t)dB*64 + 32 + 4*l] =
                make_uint4(pk2(b0,b1), pk2(b2,b3), pk2(b4,b5), pk2(b6,b7));
        }
    }
}

// y2 = relu(agg2 @ w2 + b2) via MFMA -> bf16 (pre-BN); fused BN stats.
__global__ __launch_bounds__(256) void gemm64relu_kernel(const unsigned int* __restrict__ xcat,
                                                         const unsigned int* __restrict__ W2g,
                                                         const float* __restrict__ b,
                                                         unsigned short* __restrict__ y,
                                                         float* __restrict__ sums)
{
    __shared__ __align__(16) unsigned short As[64][72];
    __shared__ float sm[256], sq[256];
    const int tid = threadIdx.x;
    const int w = tid >> 6, lane = tid & 63, lr = lane & 15, lg = lane >> 4;
    union { uint4 u; bf16x8 v; } b0, b1;
    b0.u = ((const uint4*)W2g)[(w*2 + 0)*64 + lane];
    b1.u = ((const uint4*)W2g)[(w*2 + 1)*64 + lane];
    float bc = b[w*16 + lr];
    const int srow = tid >> 2, squad = tid & 3;
    float s = 0.f, q = 0.f;
    for (int tile = blockIdx.x; tile < NT/64; tile += gridDim.x) {
        int rbase = tile*64;
        __syncthreads();
        {
            const unsigned int* src = &xcat[(size_t)(rbase + srow)*64 + 32 + squad*8];
            unsigned int* dst = (unsigned int*)&As[srow][0] + squad*8;
            *(uint4*)(dst)     = *(const uint4*)(src);
            *(uint4*)(dst + 4) = *(const uint4*)(src + 4);
        }
        __syncthreads();
        #pragma unroll
        for (int rt = 0; rt < 4; ++rt) {
            bf16x8 a0 = *(const bf16x8*)&As[rt*16 + lr][lg*8];
            bf16x8 a1 = *(const bf16x8*)&As[rt*16 + lr][32 + lg*8];
            f32x4 acc = {0.f, 0.f, 0.f, 0.f};
            acc = __builtin_amdgcn_mfma_f32_16x16x32_bf16(a0, b0.v, acc, 0, 0, 0);
            acc = __builtin_amdgcn_mfma_f32_16x16x32_bf16(a1, b1.v, acc, 0, 0, 0);
            #pragma unroll
            for (int r = 0; r < 4; ++r) {
                float v = fmaxf(acc[r] + bc, 0.f);
                y[(size_t)(rbase + rt*16 + lg*4 + r)*64 + w*16 + lr] = f2bu(v);
                s += v; q += v*v;
            }
        }
    }
    sm[tid] = s; sq[tid] = q;
    __syncthreads();
    if (tid < 64) {
        int base = (tid >> 4)*64 + (tid & 15);
        atomicAdd(&sums[tid],      sm[base] + sm[base+16] + sm[base+32] + sm[base+48]);
        atomicAdd(&sums[64 + tid], sq[base] + sq[base+16] + sq[base+32] + sq[base+48]);
    }
}

// ---------------- fused 2-layer 8-step LSTM on MFMA (3 barriers/step) --------
#define LROW 328
__global__ __launch_bounds__(256, 2) void lstm_mfma_kernel(
    const unsigned int* __restrict__ xcat,
    const unsigned int* __restrict__ y2,
    const float* __restrict__ sums2, const float* __restrict__ g2,
    const float* __restrict__ be2,
    const unsigned int* __restrict__ W1f, const unsigned int* __restrict__ W2f,
    const float* __restrict__ bs1, const float* __restrict__ bs2,
    float* __restrict__ out)
{
    __shared__ __align__(16) unsigned short xb[16][LROW];
    const int tid  = threadIdx.x;
    const int w    = tid >> 6, lane = tid & 63;
    const int lr   = lane & 15;
    const int lg   = lane >> 4;
    const int nb0  = blockIdx.x * 16;

    uint4 w1f[4][6], w2f[4][4];
    {
        const uint4* p1 = (const uint4*)W1f;
        #pragma unroll
        for (int nt = 0; nt < 4; ++nt)
            #pragma unroll
            for (int ks = 0; ks < 6; ++ks)
                w1f[nt][ks] = p1[((w*4 + nt)*6 + ks)*64 + lane];
        const uint4* p2 = (const uint4*)W2f;
        #pragma unroll
        for (int nt = 0; nt < 4; ++nt)
            #pragma unroll
            for (int ks = 0; ks < 4; ++ks)
                w2f[nt][ks] = p2[((w*4 + nt)*4 + ks)*64 + lane];
    }
    float b1v[4], b2v[4];
    #pragma unroll
    for (int nt = 0; nt < 4; ++nt) {
        b1v[nt] = bs1[nt*64 + w*16 + lr];
        b2v[nt] = bs2[nt*64 + w*16 + lr];
    }

    const int sn = tid >> 4, k0 = (tid & 15)*8;
    float ax[8], bx[8];
    if (k0 >= 64) {
        #pragma unroll
        for (int j = 0; j < 8; ++j) {
            int c = k0 - 64 + j;
            float mu  = sums2[c] * (1.0f/NT);
            float var = sums2[64 + c] * (1.0f/NT) - mu*mu;
            float a = rsqrtf(var + BNEPS) * g2[c];
            ax[j] = a; bx[j] = be2[c] - mu*a;
        }
    }

    for (int i = tid; i < 16*24; i += 256) {
        int n = i / 24, kk = 128 + (i % 24)*8;
        uint4 z; z.x = z.y = z.z = z.w = 0u;
        *(uint4*)&xb[n][kk] = z;
    }

    auto stage = [&](int step) {
        size_t row = (size_t)(step*NNODES + nb0 + sn);
        uint4 raw;
        if (k0 < 64) {
            raw = *(const uint4*)&xcat[row*64 + (k0 >> 1)];
        } else {
            raw = *(const uint4*)&y2[row*32 + ((k0 - 64) >> 1)];
            unsigned int um[4] = {raw.x, raw.y, raw.z, raw.w};
            #pragma unroll
            for (int m = 0; m < 4; ++m) {
                float v0 = fmaf(ax[2*m],   u2f(um[m] << 16),         bx[2*m]);
                float v1 = fmaf(ax[2*m+1], u2f(um[m] & 0xffff0000u), bx[2*m+1]);
                um[m] = pk2(v0, v1);
            }
            raw.x = um[0]; raw.y = um[1]; raw.z = um[2]; raw.w = um[3];
        }
        *(uint4*)&xb[sn][k0] = raw;
    };
    stage(0);
    float c1[4] = {0.f,0.f,0.f,0.f}, c2[4] = {0.f,0.f,0.f,0.f};

    for (int step = 0; step < 8; ++step) {
        __syncthreads();                    // B_a

        f32x4 acc[4];
        #pragma unroll
        for (int nt = 0; nt < 4; ++nt) { acc[nt][0]=0.f; acc[nt][1]=0.f; acc[nt][2]=0.f; acc[nt][3]=0.f; }
        #pragma unroll
        for (int ks = 0; ks < 6; ++ks) {
            bf16x8 a = *(const bf16x8*)&xb[lr][ks*32 + lg*8];
            #pragma unroll
            for (int nt = 0; nt < 4; ++nt) {
                union { uint4 u; bf16x8 v; } wb; wb.u = w1f[nt][ks];
                acc[nt] = __builtin_amdgcn_mfma_f32_16x16x32_bf16(a, wb.v, acc[nt], 0, 0, 0);
            }
        }
        __syncthreads();                    // B_b

        #pragma unroll
        for (int r = 0; r < 4; ++r) {
            float zi = acc[0][r] + b1v[0];
            float zf = acc[1][r] + b1v[1];
            float zg = acc[2][r] + b1v[2];
            float zo = acc[3][r] + b1v[3];
            float c  = fsig(zf)*c1[r] + fsig(zi)*ftanh(zg);
            c1[r] = c;
            float hv = fsig(zo)*ftanh(c);
            int node = lg*4 + r;
            xb[node][128 + w*16 + lr] = f2bu(hv);
            if (step == 7) out[(size_t)(nb0 + node)*143 + w*16 + lr] = hv;
        }
        if (step < 7) stage(step + 1);
        __syncthreads();                    // B_c

        int rb = 192 + 64*((step+1)&1);
        int wb2 = 192 + 64*(step&1);
        #pragma unroll
        for (int nt = 0; nt < 4; ++nt) { acc[nt][0]=0.f; acc[nt][1]=0.f; acc[nt][2]=0.f; acc[nt][3]=0.f; }
        #pragma unroll
        for (int ks = 0; ks < 2; ++ks) {
            bf16x8 a = *(const bf16x8*)&xb[lr][128 + ks*32 + lg*8];
            #pragma unroll
            for (int nt = 0; nt < 4; ++nt) {
                union { uint4 u; bf16x8 v; } wbv; wbv.u = w2f[nt][ks];
                acc[nt] = __builtin_amdgcn_mfma_f32_16x16x32_bf16(a, wbv.v, acc[nt], 0, 0, 0);
            }
        }
        #pragma unroll
        for (int ks = 0; ks < 2; ++ks) {
            bf16x8 a = *(const bf16x8*)&xb[lr][rb + ks*32 + lg*8];
            #pragma unroll
            for (int nt = 0; nt < 4; ++nt) {
                union { uint4 u; bf16x8 v; } wbv; wbv.u = w2f[nt][2+ks];
                acc[nt] = __builtin_amdgcn_mfma_f32_16x16x32_bf16(a, wbv.v, acc[nt], 0, 0, 0);
            }
        }
        #pragma unroll
        for (int r = 0; r < 4; ++r) {
            float zi = acc[0][r] + b2v[0];
            float zf = acc[1][r] + b2v[1];
            float zg = acc[2][r] + b2v[2];
            float zo = acc[3][r] + b2v[3];
            float c  = fsig(zf)*c2[r] + fsig(zi)*ftanh(zg);
            c2[r] = c;
            float hv = fsig(zo)*ftanh(c);
            int node = lg*4 + r;
            xb[node][wb2 + w*16 + lr] = f2bu(hv);
            if (step == 7) out[(size_t)(nb0 + node)*143 + 64 + w*16 + lr] = hv;
        }
    }
}

__global__ __launch_bounds__(256) void sfeat_kernel(const float* __restrict__ X,
                                                    float* __restrict__ out)
{
    int gid = blockIdx.x*256 + threadIdx.x;
    if (gid >= NNODES*15) return;
    int n = gid/15, i = gid%15;
    float v = (i < 8) ? X[(size_t)n*8 + i]
                      : X[((size_t)(i-7)*NNODES + n)*8 + 7];
    out[(size_t)n*143 + 128 + i] = v;
}

extern "C" void kernel_launch(void* const* d_in, const int* in_sizes, int n_in,
                              void* d_out, int out_size, void* d_ws, size_t ws_size,
                              hipStream_t stream)
{
    (void)in_sizes; (void)n_in; (void)out_size; (void)ws_size;
    const float* X    = (const float*)d_in[0];
    const int*   ei   = (const int*)d_in[1];
    const float* ew   = (const float*)d_in[2];
    const float* w1   = (const float*)d_in[3];
    const float* b1   = (const float*)d_in[4];
    const float* w2   = (const float*)d_in[5];
    const float* b2   = (const float*)d_in[6];
    const float* g1   = (const float*)d_in[7];
    const float* be1  = (const float*)d_in[8];
    const float* g2   = (const float*)d_in[9];
    const float* be2  = (const float*)d_in[10];
    const float* wih1 = (const float*)d_in[11];
    const float* whh1 = (const float*)d_in[12];
    const float* bih1 = (const float*)d_in[13];
    const float* bhh1 = (const float*)d_in[14];
    const float* wih2 = (const float*)d_in[15];
    const float* whh2 = (const float*)d_in[16];
    const float* bih2 = (const float*)d_in[17];
    const float* bhh2 = (const float*)d_in[18];
    float* out = (float*)d_out;
    float* ws  = (float*)d_ws;

    const int* src = ei;
    const int* dst = ei + NE;

    // workspace layout (word offsets)
    float* sums      = ws;                                //  256 [zeroed]
    float* dinv      = ws + 256;                          //  NT
    int*   rowptr    = (int*)(ws + 80256);                //  NT+1 (pad 4)
    int*   binTotal  = (int*)(ws + 160260);               //  625 (pad 640)
    int*   bucketbase= (int*)(ws + 160900);               //  626 (pad 640)
    int*   histmat   = (int*)(ws + 161540);               //  256*640
    int*   offmatT   = (int*)(ws + 325380);               //  625*256
    unsigned char* urank = (unsigned char*)(ws + 485380); //  NE bytes
    uint2* esort     = (uint2*)(ws + 805384);             //  NE*2 w
    unsigned int* x8 = (unsigned int*)(ws + 805384);      //  NT*16 w (alias: esort dead by then)
    unsigned int* y2 = (unsigned int*)(ws + 805384);      //  NT*32 w (alias: x8 dead by then)
    unsigned int* epack = (unsigned int*)(ws + 3365384);  //  NE w
    unsigned int* Xb = (unsigned int*)(ws + 4645384);     //  NT*4
    uint4* agg8b     = (uint4*)(ws + 4965384);            //  NT*4 w (bf16 rows)
    unsigned int* y1 = (unsigned int*)(ws + 5605384);     //  NT*32
    unsigned int* xcat = (unsigned int*)(ws + 8165384);   //  NT*64
    unsigned int* W1f  = (unsigned int*)(ws + 13285384);  //  24576
    unsigned int* W2f  = W1f + 24576;                     //  16384
    float* bs1 = (float*)(W2f + 16384);                   //  256
    float* bs2 = bs1 + 256;                               //  256
    unsigned int* W2g  = (unsigned int*)(bs2 + 256);      //  2048
    unsigned int* W1g  = W2g + 2048;                      //  1024

    hipMemsetAsync(ws, 0, 256 * 4, stream);

    prep_w_kernel<<<174, 256, 0, stream>>>(wih1,whh1,bih1,bhh1,
                                           wih2,whh2,bih2,bhh2,
                                           w1, w2,
                                           W1f,W2f,bs1,bs2,W2g,W1g);
    // deterministic two-level counting sort (no global atomics) + xconv
    sortA1_kernel<<<256, 256, 0, stream>>>(dst, X, Xb, histmat);
    sortA2a_kernel<<<NBKT, 256, 0, stream>>>(histmat, offmatT, binTotal);
    sortA2b_kernel<<<1, 1024, 0, stream>>>(binTotal, bucketbase, rowptr);
    sortA3_kernel<<<256, 256, 0, stream>>>(src, dst, ew, offmatT, bucketbase, esort);
    sortB1_kernel<<<NBKT, 256, 0, stream>>>(bucketbase, esort, urank, rowptr, dinv);
    // B2 + layer-1 gather fused (epack kept in LDS)
    sortB2g8_kernel<<<NBKT, 256, 0, stream>>>(bucketbase, esort, urank, rowptr, dinv,
                                              epack, (const uint4*)Xb, agg8b);

    // GCN layer 1 GEMM
    gemm8relu_kernel<<<320, 256, 0, stream>>>(agg8b, W1g, b1, (unsigned short*)y1, sums);

    // BN apply -> bf16 x1 (xcat[0:32]) + fp8 gather table x8
    xbn8_kernel<<<(NT*16+255)/256, 256, 0, stream>>>(y1, sums, g1, be1, xcat, x8);

    // GCN layer 2: fp8 gather (dual-dst MLP), MFMA GEMM (BN2 fused into LSTM)
    gather64_kernel<<<2048, 256, 0, stream>>>(rowptr, epack, x8, dinv, xcat);
    gemm64relu_kernel<<<320, 256, 0, stream>>>(xcat, W2g, b2, (unsigned short*)y2, sums + 128);

    // fused MFMA LSTM + skip features
    lstm_mfma_kernel<<<NNODES/16, 256, 0, stream>>>(xcat, y2, sums + 128, g2, be2,
                                                    W1f, W2f, bs1, bs2, out);
    sfeat_kernel<<<(NNODES*15+255)/256, 256, 0, stream>>>(X, out);
}

// Round 14
// 174.726 us; speedup vs baseline: 1.1593x; 1.0286x over previous
//
#include <hip/hip_runtime.h>
#include <hip/hip_bf16.h>
#include <math.h>

#define NNODES 10000
#define NT     80000
#define NE     1280000
#define NBKT   625       // coarse buckets = NT/128
#define CHUNK  5000      // edges per A-block = NE/256
#define EPB    3072      // max edges kept in LDS per bucket (mean 2048, +22 sigma)
#define BNEPS  1e-5f

typedef __bf16 bf16x8 __attribute__((ext_vector_type(8)));
typedef float  f32x4  __attribute__((ext_vector_type(4)));
typedef float  f32x2  __attribute__((ext_vector_type(2)));

__device__ __forceinline__ float frcp(float x){ return __builtin_amdgcn_rcpf(x); }
__device__ __forceinline__ float fsig(float x){ return frcp(1.0f + __expf(-x)); }
__device__ __forceinline__ float ftanh(float x){ return 1.0f - 2.0f*frcp(1.0f + __expf(2.0f*x)); }
__device__ __forceinline__ float u2f(unsigned int u){ union{unsigned int u; float f;} c; c.u=u; return c.f; }
__device__ __forceinline__ unsigned int f2u(float f){ union{float f; unsigned int u;} c; c.f=f; return c.u; }
__device__ __forceinline__ unsigned short f2bu(float v){ __hip_bfloat16 h = __float2bfloat16(v); return *(unsigned short*)&h; }
__device__ __forceinline__ unsigned int pk2(float a, float b){ return (unsigned int)f2bu(a) | ((unsigned int)f2bu(b) << 16); }
// 15-bit float decode: 8-bit exp, 6-bit mantissa, positive only
__device__ __forceinline__ float dec15(unsigned int p){ return u2f((p & 0x7fffu) << 17); }

// ---- fused: weight prep (blocks 256..429) + coarse histogram/xconv (0..255) --
__global__ __launch_bounds__(256) void prepA1_kernel(
    const int* __restrict__ dst, const float* __restrict__ X,
    unsigned int* __restrict__ Xb, int* __restrict__ histmat,
    const float* __restrict__ wih1, const float* __restrict__ whh1,
    const float* __restrict__ bih1, const float* __restrict__ bhh1,
    const float* __restrict__ wih2, const float* __restrict__ whh2,
    const float* __restrict__ bih2, const float* __restrict__ bhh2,
    const float* __restrict__ w1g, const float* __restrict__ w2g,
    unsigned int* __restrict__ W1f, unsigned int* __restrict__ W2f,
    float* __restrict__ bs1, float* __restrict__ bs2,
    unsigned int* __restrict__ W2g, unsigned int* __restrict__ W1g)
{
    __shared__ int h[NBKT];
    if (blockIdx.x < 256) {
        for (int i = threadIdx.x; i < NBKT; i += 256) h[i] = 0;
        __syncthreads();
        int base = blockIdx.x*CHUNK;
        for (int i = threadIdx.x; i < CHUNK; i += 256)
            atomicAdd(&h[dst[base + i] >> 7], 1);
        for (int i = threadIdx.x; i < 1250; i += 256) {
            int gid = blockIdx.x*1250 + i;
            float2 v = *(const float2*)&X[(size_t)gid*2];
            Xb[gid] = pk2(v.x, v.y);
        }
        __syncthreads();
        for (int i = threadIdx.x; i < NBKT; i += 256)
            histmat[blockIdx.x*640 + i] = h[i];
        return;
    }
    int gid = (blockIdx.x - 256)*256 + threadIdx.x;
    if (gid < 24576) {
        int i = gid & 3, lane = (gid>>2)&63, rest = gid>>8;
        int ks = rest % 6; rest /= 6;
        int nt = rest & 3, w = rest >> 2;
        int gate = nt*64 + w*16 + (lane & 15);
        int k = ks*32 + ((lane>>4)&3)*8 + 2*i;
        float v0 = (k     < 128) ? wih1[gate*128 + k]       : whh1[gate*64 + (k-128)];
        float v1 = (k + 1 < 128) ? wih1[gate*128 + k + 1]   : whh1[gate*64 + (k+1-128)];
        W1f[gid] = pk2(v0, v1);
    } else if (gid < 40960) {
        int r = gid - 24576;
        int i = r & 3, lane = (r>>2)&63, rest = r>>8;
        int ks = rest & 3; rest >>= 2;
        int nt = rest & 3, w = rest >> 2;
        int gate = nt*64 + w*16 + (lane & 15);
        int k = ks*32 + ((lane>>4)&3)*8 + 2*i;
        float v0 = (k     < 64) ? wih2[gate*64 + k]     : whh2[gate*64 + (k-64)];
        float v1 = (k + 1 < 64) ? wih2[gate*64 + k + 1] : whh2[gate*64 + (k+1-64)];
        W2f[r] = pk2(v0, v1);
    } else if (gid < 41216) {
        int j = gid - 40960; bs1[j] = bih1[j] + bhh1[j];
    } else if (gid < 41472) {
        int j = gid - 41216; bs2[j] = bih2[j] + bhh2[j];
    } else if (gid < 43520) {
        int r = gid - 41472;
        int i = r & 3, lane = (r>>2)&63, rest = r>>8;
        int ks = rest & 1, w = rest >> 1;
        int col = w*16 + (lane & 15);
        int k = ks*32 + ((lane>>4)&3)*8 + 2*i;
        W2g[r] = pk2(w2g[k*64 + col], w2g[(k+1)*64 + col]);
    } else if (gid < 44544) {
        int r = gid - 43520;
        int i = r & 3, lane = (r>>2)&63, w = r>>8;
        int col = w*16 + (lane & 15);
        int k = ((lane>>4)&3)*8 + 2*i;
        float v0 = (k     < 8) ? w1g[k*64 + col]     : 0.f;
        float v1 = (k + 1 < 8) ? w1g[(k+1)*64 + col] : 0.f;
        W1g[r] = pk2(v0, v1);
    }
}

__global__ __launch_bounds__(256) void sortA2a_kernel(const int* __restrict__ histmat,
                                                      int* __restrict__ offmatT,
                                                      int* __restrict__ binTotal)
{
    __shared__ int v[256];
    int b = blockIdx.x, t = threadIdx.x;
    int x = histmat[t*640 + b];
    v[t] = x;
    __syncthreads();
    for (int off = 1; off < 256; off <<= 1) {
        int y = (t >= off) ? v[t-off] : 0;
        __syncthreads();
        v[t] += y;
        __syncthreads();
    }
    offmatT[b*256 + t] = v[t] - x;
    if (t == 255) binTotal[b] = v[255];
}

__global__ __launch_bounds__(1024) void sortA2b_kernel(const int* __restrict__ binTotal,
                                                       int* __restrict__ bucketbase,
                                                       int* __restrict__ rowptr)
{
    __shared__ int part[1024];
    int t = threadIdx.x;
    int v = (t < NBKT) ? binTotal[t] : 0;
    part[t] = v;
    __syncthreads();
    for (int off = 1; off < 1024; off <<= 1) {
        int y = (t >= off) ? part[t-off] : 0;
        __syncthreads();
        part[t] += y;
        __syncthreads();
    }
    if (t < NBKT) bucketbase[t] = part[t] - v;
    if (t == 0) { bucketbase[NBKT] = NE; rowptr[NT] = NE; }
}

__global__ __launch_bounds__(256) void sortA3_kernel(const int* __restrict__ src,
                                                     const int* __restrict__ dst,
                                                     const float* __restrict__ ew,
                                                     const int* __restrict__ offmatT,
                                                     const int* __restrict__ bucketbase,
                                                     uint2* __restrict__ esort)
{
    __shared__ int cur[NBKT];
    int blk = blockIdx.x;
    for (int i = threadIdx.x; i < NBKT; i += 256)
        cur[i] = bucketbase[i] + offmatT[i*256 + blk];
    __syncthreads();
    int base = blk*CHUNK;
    for (int i = threadIdx.x; i < CHUNK; i += 256) {
        int e = base + i;
        int d = dst[e];
        int pos = atomicAdd(&cur[d >> 7], 1);
        uint2 r;
        r.x = (unsigned int)src[e] | ((unsigned int)(d & 127) << 17);
        r.y = f2u(ew[e]);
        esort[pos] = r;
    }
}

__global__ __launch_bounds__(256) void sortB1_kernel(const int* __restrict__ bucketbase,
                                                     const uint2* __restrict__ esort,
                                                     unsigned char* __restrict__ urank,
                                                     int* __restrict__ rowptr,
                                                     float* __restrict__ dinv)
{
    __shared__ int cnt[128];
    __shared__ float dg[128];
    __shared__ int ptr[128];
    int bin = blockIdx.x, t = threadIdx.x;
    if (t < 128) { cnt[t] = 0; dg[t] = 0.f; }
    __syncthreads();
    int base = bucketbase[bin], end = bucketbase[bin+1];
    for (int i = base + t; i < end; i += 256) {
        uint2 r = esort[i];
        int dl = (r.x >> 17) & 127;
        int rk = atomicAdd(&cnt[dl], 1);
        atomicAdd(&dg[dl], u2f(r.y));
        urank[i] = (unsigned char)rk;
    }
    __syncthreads();
    if (t < 128) ptr[t] = cnt[t];
    __syncthreads();
    for (int off = 1; off < 128; off <<= 1) {
        int y = (t >= off && t < 128) ? ptr[t-off] : 0;
        __syncthreads();
        if (t < 128) ptr[t] += y;
        __syncthreads();
    }
    if (t < 128) {
        rowptr[bin*128 + t] = base + ptr[t] - cnt[t];
        dinv[bin*128 + t]   = rsqrtf(dg[t] + 1.0f);
    }
}

// B2 + layer-1 gather + layer-1 MFMA GEMM (+relu, BN stats) all in one block:
// bucket = 128 dsts = two 64-row GEMM tiles. y1 (pre-BN bf16) written directly.
__global__ __launch_bounds__(256) void sortB2g8m_kernel(const int* __restrict__ bucketbase,
                                                        const uint2* __restrict__ esort,
                                                        const unsigned char* __restrict__ urank,
                                                        const int* __restrict__ rowptr,
                                                        const float* __restrict__ dinv,
                                                        unsigned int* __restrict__ epack,
                                                        const uint4* __restrict__ Xb,
                                                        const unsigned int* __restrict__ W1g,
                                                        const float* __restrict__ b1,
                                                        unsigned short* __restrict__ y1,
                                                        float* __restrict__ sums)
{
    __shared__ unsigned int eld[EPB];
    __shared__ __align__(16) unsigned short As[128][8];
    __shared__ float smc[256][4], sqc[256][4];
    int bin = blockIdx.x;
    int base = bucketbase[bin], end = bucketbase[bin+1];
    int cnt = end - base;
    for (int i = threadIdx.x; i < cnt; i += 256) {
        uint2 r = esort[base + i];
        int s = r.x & 0x1FFFF;
        int d = bin*128 + ((r.x >> 17) & 127);
        float w = u2f(r.y) * dinv[s];
        unsigned int p15 = (f2u(w) + (1u << 16)) >> 17;
        unsigned int pv = ((unsigned int)s << 15) | p15;
        int pos = rowptr[d] + (int)urank[base + i];
        epack[pos] = pv;
        int lpos = pos - base;
        if (lpos < EPB) eld[lpos] = pv;
    }
    __syncthreads();
    // gather phase: 2 threads per dst
    {
        int t = threadIdx.x;
        int dl = t >> 1, par = t & 1;
        int d = bin*128 + dl;
        int beg = rowptr[d], endd = rowptr[d+1];
        float acc[8];
        #pragma unroll
        for (int k = 0; k < 8; ++k) acc[k] = 0.f;
        for (int i = beg + par; i < endd; i += 2) {
            int lpos = i - base;
            unsigned int p = (lpos < EPB) ? eld[lpos] : epack[i];
            float nrm = dec15(p);
            uint4 xv = Xb[p >> 15];
            unsigned int um[4] = {xv.x, xv.y, xv.z, xv.w};
            #pragma unroll
            for (int m = 0; m < 4; ++m) {
                acc[2*m]   = fmaf(nrm, u2f(um[m] << 16),         acc[2*m]);
                acc[2*m+1] = fmaf(nrm, u2f(um[m] & 0xffff0000u), acc[2*m+1]);
            }
        }
        #pragma unroll
        for (int k = 0; k < 8; ++k) acc[k] += __shfl_xor(acc[k], 1);
        if (par == 0) {
            float dv = dinv[d];
            uint4 xd = Xb[d];
            unsigned int ud[4] = {xd.x, xd.y, xd.z, xd.w};
            #pragma unroll
            for (int m = 0; m < 4; ++m) {
                acc[2*m]   = dv * fmaf(dv, u2f(ud[m] << 16),         acc[2*m]);
                acc[2*m+1] = dv * fmaf(dv, u2f(ud[m] & 0xffff0000u), acc[2*m+1]);
            }
            *(uint4*)&As[dl][0] = make_uint4(pk2(acc[0],acc[1]), pk2(acc[2],acc[3]),
                                             pk2(acc[4],acc[5]), pk2(acc[6],acc[7]));
        }
    }
    __syncthreads();
    // MFMA phase: wave w -> row-tiles 2w, 2w+1; all 4 col-tiles
    {
        int t = threadIdx.x;
        int w = t >> 6, lane = t & 63, lr = lane & 15, lg = lane >> 4;
        uint4 bfrag[4];
        float bb[4];
        #pragma unroll
        for (int nt = 0; nt < 4; ++nt) {
            bfrag[nt] = ((const uint4*)W1g)[nt*64 + lane];
            bb[nt] = b1[nt*16 + lr];
        }
        float sc[4] = {0.f,0.f,0.f,0.f}, qc[4] = {0.f,0.f,0.f,0.f};
        #pragma unroll
        for (int rr = 0; rr < 2; ++rr) {
            int rt = w*2 + rr;
            bf16x8 a = {};
            if (lg == 0) a = *(const bf16x8*)&As[rt*16 + lr][0];
            #pragma unroll
            for (int nt = 0; nt < 4; ++nt) {
                union { uint4 u; bf16x8 v; } bw; bw.u = bfrag[nt];
                f32x4 acc = {0.f, 0.f, 0.f, 0.f};
                acc = __builtin_amdgcn_mfma_f32_16x16x32_bf16(a, bw.v, acc, 0, 0, 0);
                #pragma unroll
                for (int r = 0; r < 4; ++r) {
                    float v = fmaxf(acc[r] + bb[nt], 0.f);
                    int row = bin*128 + rt*16 + lg*4 + r;
                    y1[(size_t)row*64 + nt*16 + lr] = f2bu(v);
                    sc[nt] += v; qc[nt] += v*v;
                }
            }
        }
        #pragma unroll
        for (int nt = 0; nt < 4; ++nt) { smc[t][nt] = sc[nt]; sqc[t][nt] = qc[nt]; }
        __syncthreads();
        if (t < 64) {
            int nt = t >> 4, lr2 = t & 15;
            float s = 0.f, q = 0.f;
            #pragma unroll
            for (int w4 = 0; w4 < 4; ++w4)
                #pragma unroll
                for (int lg2 = 0; lg2 < 4; ++lg2) {
                    int idx = w4*64 + lg2*16 + lr2;
                    s += smc[idx][nt]; q += sqc[idx][nt];
                }
            atomicAdd(&sums[t], s);
            atomicAdd(&sums[64 + t], q);
        }
    }
}

// BN apply once: y1 (pre-BN bf16) -> BN'd x1 bf16 into xcat[0:32]
//                               -> BN'd x1 fp8 e4m3 table x8 [NT][64]
__global__ __launch_bounds__(256) void xbn8_kernel(const unsigned int* __restrict__ y1,
                                                   const float* __restrict__ sums,
                                                   const float* __restrict__ g,
                                                   const float* __restrict__ be,
                                                   unsigned int* __restrict__ xcat,
                                                   unsigned int* __restrict__ x8)
{
    __shared__ float axs[64], bxs[64];
    int tid = threadIdx.x;
    if (tid < 64) {
        float mu  = sums[tid] * (1.0f/NT);
        float var = sums[64 + tid] * (1.0f/NT) - mu*mu;
        float a = rsqrtf(var + BNEPS) * g[tid];
        axs[tid] = a; bxs[tid] = be[tid] - mu*a;
    }
    __syncthreads();
    int gid = blockIdx.x*256 + tid;            // over NT*16 channel-quads
    if (gid >= NT*16) return;
    int c4 = gid & 15, n = gid >> 4;
    int c0 = c4*4;
    uint2 yy = *(const uint2*)&y1[(size_t)n*32 + 2*c4];
    float v0 = fmaf(axs[c0+0], u2f(yy.x << 16),         bxs[c0+0]);
    float v1 = fmaf(axs[c0+1], u2f(yy.x & 0xffff0000u), bxs[c0+1]);
    float v2 = fmaf(axs[c0+2], u2f(yy.y << 16),         bxs[c0+2]);
    float v3 = fmaf(axs[c0+3], u2f(yy.y & 0xffff0000u), bxs[c0+3]);
    *(uint2*)&xcat[(size_t)n*64 + 2*c4] = make_uint2(pk2(v0, v1), pk2(v2, v3));
    int p8 = 0;
    p8 = __builtin_amdgcn_cvt_pk_fp8_f32(v0, v1, p8, false);
    p8 = __builtin_amdgcn_cvt_pk_fp8_f32(v2, v3, p8, true);
    x8[(size_t)n*16 + c4] = (unsigned int)p8;
}

// 64-ch gather from fp8 table: 8 edges/wave over TWO dsts concurrently.
// Self-loop from bf16 xcat[0:32]; aggregate (bf16) -> xcat[32:64].
__global__ __launch_bounds__(256) void gather64_kernel(const int* __restrict__ rowptr,
                                                       const unsigned int* __restrict__ epack,
                                                       const unsigned int* __restrict__ x8,
                                                       const float* __restrict__ dinv,
                                                       unsigned int* __restrict__ xcat)
{
    int lane = threadIdx.x & 63;
    int g = lane >> 3;                        // edge slot 0..7
    int l = lane & 7;                         // channel octet (8 ch = 2 dwords fp8)
    int gwave = blockIdx.x*4 + (threadIdx.x >> 6);
    int nwaves = gridDim.x*4;
    for (int dp = gwave; dp < NT/2; dp += nwaves) {
        int dA = dp*2, dB = dA + 1;
        int begA = rowptr[dA], endA = rowptr[dA+1];
        int begB = endA, endB = rowptr[dB+1];
        int nA = endA - begA, nB = endB - begB;
        int n = nA > nB ? nA : nB;
        int clA = (endA > begA) ? endA - 1 : 0;
        int clB = (endB > begB) ? endB - 1 : 0;
        float a0=0.f,a1=0.f,a2=0.f,a3=0.f,a4=0.f,a5=0.f,a6=0.f,a7=0.f;
        float b0=0.f,b1=0.f,b2=0.f,b3=0.f,b4=0.f,b5=0.f,b6=0.f,b7=0.f;
        for (int i = 0; i < n; i += 8) {
            int iA = begA + i + g;
            bool vA = iA < endA;
            unsigned int pA = epack[vA ? iA : clA];
            float nrmA = vA ? dec15(pA) : 0.f;
            int iB = begB + i + g;
            bool vB = iB < endB;
            unsigned int pB = epack[vB ? iB : clB];
            float nrmB = vB ? dec15(pB) : 0.f;
            uint2 xvA = *(const uint2*)&x8[(size_t)(pA >> 15)*16 + 2*l];
            uint2 xvB = *(const uint2*)&x8[(size_t)(pB >> 15)*16 + 2*l];
            f32x2 qa0 = __builtin_amdgcn_cvt_pk_f32_fp8((int)xvA.x, false);
            f32x2 qa1 = __builtin_amdgcn_cvt_pk_f32_fp8((int)xvA.x, true);
            f32x2 qa2 = __builtin_amdgcn_cvt_pk_f32_fp8((int)xvA.y, false);
            f32x2 qa3 = __builtin_amdgcn_cvt_pk_f32_fp8((int)xvA.y, true);
            a0 = fmaf(nrmA, qa0[0], a0); a1 = fmaf(nrmA, qa0[1], a1);
            a2 = fmaf(nrmA, qa1[0], a2); a3 = fmaf(nrmA, qa1[1], a3);
            a4 = fmaf(nrmA, qa2[0], a4); a5 = fmaf(nrmA, qa2[1], a5);
            a6 = fmaf(nrmA, qa3[0], a6); a7 = fmaf(nrmA, qa3[1], a7);
            f32x2 qb0 = __builtin_amdgcn_cvt_pk_f32_fp8((int)xvB.x, false);
            f32x2 qb1 = __builtin_amdgcn_cvt_pk_f32_fp8((int)xvB.x, true);
            f32x2 qb2 = __builtin_amdgcn_cvt_pk_f32_fp8((int)xvB.y, false);
            f32x2 qb3 = __builtin_amdgcn_cvt_pk_f32_fp8((int)xvB.y, true);
            b0 = fmaf(nrmB, qb0[0], b0); b1 = fmaf(nrmB, qb0[1], b1);
            b2 = fmaf(nrmB, qb1[0], b2); b3 = fmaf(nrmB, qb1[1], b3);
            b4 = fmaf(nrmB, qb2[0], b4); b5 = fmaf(nrmB, qb2[1], b5);
            b6 = fmaf(nrmB, qb3[0], b6); b7 = fmaf(nrmB, qb3[1], b7);
        }
        #pragma unroll
        for (int off = 8; off < 64; off <<= 1) {
            a0 += __shfl_xor(a0, off); a1 += __shfl_xor(a1, off);
            a2 += __shfl_xor(a2, off); a3 += __shfl_xor(a3, off);
            a4 += __shfl_xor(a4, off); a5 += __shfl_xor(a5, off);
            a6 += __shfl_xor(a6, off); a7 += __shfl_xor(a7, off);
            b0 += __shfl_xor(b0, off); b1 += __shfl_xor(b1, off);
            b2 += __shfl_xor(b2, off); b3 += __shfl_xor(b3, off);
            b4 += __shfl_xor(b4, off); b5 += __shfl_xor(b5, off);
            b6 += __shfl_xor(b6, off); b7 += __shfl_xor(b7, off);
        }
        if (g == 0) {
            float dvA = dinv[dA];
            uint4 xdA = *(const uint4*)&xcat[(size_t)dA*64 + 4*l];
            a0 = dvA * fmaf(dvA, u2f(xdA.x << 16),         a0);
            a1 = dvA * fmaf(dvA, u2f(xdA.x & 0xffff0000u), a1);
            a2 = dvA * fmaf(dvA, u2f(xdA.y << 16),         a2);
            a3 = dvA * fmaf(dvA, u2f(xdA.y & 0xffff0000u), a3);
            a4 = dvA * fmaf(dvA, u2f(xdA.z << 16),         a4);
            a5 = dvA * fmaf(dvA, u2f(xdA.z & 0xffff0000u), a5);
            a6 = dvA * fmaf(dvA, u2f(xdA.w << 16),         a6);
            a7 = dvA * fmaf(dvA, u2f(xdA.w & 0xffff0000u), a7);
            *(uint4*)&xcat[(size_t)dA*64 + 32 + 4*l] =
                make_uint4(pk2(a0,a1), pk2(a2,a3), pk2(a4,a5), pk2(a6,a7));
            float dvB = dinv[dB];
            uint4 xdB = *(const uint4*)&xcat[(size_t)dB*64 + 4*l];
            b0 = dvB * fmaf(dvB, u2f(xdB.x << 16),         b0);
            b1 = dvB * fmaf(dvB, u2f(xdB.x & 0xffff0000u), b1);
            b2 = dvB * fmaf(dvB, u2f(xdB.y << 16),         b2);
            b3 = dvB * fmaf(dvB, u2f(xdB.y & 0xffff0000u), b3);
            b4 = dvB * fmaf(dvB, u2f(xdB.z << 16),         b4);
            b5 = dvB * fmaf(dvB, u2f(xdB.z & 0xffff0000u), b5);
            b6 = dvB * fmaf(dvB, u2f(xdB.w << 16),         b6);
            b7 = dvB * fmaf(dvB, u2f(xdB.w & 0xffff0000u), b7);
            *(uint4*)&xcat[(size_t)dB*64 + 32 + 4*l] =
                make_uint4(pk2(b0,b1), pk2(b2,b3), pk2(b4,b5), pk2(b6,b7));
        }
    }
}

// y2 = relu(agg2 @ w2 + b2) via MFMA -> bf16 (pre-BN); fused BN stats.
__global__ __launch_bounds__(256) void gemm64relu_kernel(const unsigned int* __restrict__ xcat,
                                                         const unsigned int* __restrict__ W2g,
                                                         const float* __restrict__ b,
                                                         unsigned short* __restrict__ y,
                                                         float* __restrict__ sums)
{
    __shared__ __align__(16) unsigned short As[64][72];
    __shared__ float sm[256], sq[256];
    const int tid = threadIdx.x;
    const int w = tid >> 6, lane = tid & 63, lr = lane & 15, lg = lane >> 4;
    union { uint4 u; bf16x8 v; } b0, b1;
    b0.u = ((const uint4*)W2g)[(w*2 + 0)*64 + lane];
    b1.u = ((const uint4*)W2g)[(w*2 + 1)*64 + lane];
    float bc = b[w*16 + lr];
    const int srow = tid >> 2, squad = tid & 3;
    float s = 0.f, q = 0.f;
    for (int tile = blockIdx.x; tile < NT/64; tile += gridDim.x) {
        int rbase = tile*64;
        __syncthreads();
        {
            const unsigned int* src = &xcat[(size_t)(rbase + srow)*64 + 32 + squad*8];
            unsigned int* dst = (unsigned int*)&As[srow][0] + squad*8;
            *(uint4*)(dst)     = *(const uint4*)(src);
            *(uint4*)(dst + 4) = *(const uint4*)(src + 4);
        }
        __syncthreads();
        #pragma unroll
        for (int rt = 0; rt < 4; ++rt) {
            bf16x8 a0 = *(const bf16x8*)&As[rt*16 + lr][lg*8];
            bf16x8 a1 = *(const bf16x8*)&As[rt*16 + lr][32 + lg*8];
            f32x4 acc = {0.f, 0.f, 0.f, 0.f};
            acc = __builtin_amdgcn_mfma_f32_16x16x32_bf16(a0, b0.v, acc, 0, 0, 0);
            acc = __builtin_amdgcn_mfma_f32_16x16x32_bf16(a1, b1.v, acc, 0, 0, 0);
            #pragma unroll
            for (int r = 0; r < 4; ++r) {
                float v = fmaxf(acc[r] + bc, 0.f);
                y[(size_t)(rbase + rt*16 + lg*4 + r)*64 + w*16 + lr] = f2bu(v);
                s += v; q += v*v;
            }
        }
    }
    sm[tid] = s; sq[tid] = q;
    __syncthreads();
    if (tid < 64) {
        int base = (tid >> 4)*64 + (tid & 15);
        atomicAdd(&sums[tid],      sm[base] + sm[base+16] + sm[base+32] + sm[base+48]);
        atomicAdd(&sums[64 + tid], sq[base] + sq[base+16] + sq[base+32] + sq[base+48]);
    }
}

// ---------------- fused 2-layer 8-step LSTM on MFMA (+ sfeat) ----------------
#define LROW 328
__global__ __launch_bounds__(256, 2) void lstm_mfma_kernel(
    const unsigned int* __restrict__ xcat,
    const unsigned int* __restrict__ y2,
    const float* __restrict__ sums2, const float* __restrict__ g2,
    const float* __restrict__ be2,
    const unsigned int* __restrict__ W1f, const unsigned int* __restrict__ W2f,
    const float* __restrict__ bs1, const float* __restrict__ bs2,
    const float* __restrict__ X,
    float* __restrict__ out)
{
    __shared__ __align__(16) unsigned short xb[16][LROW];
    const int tid  = threadIdx.x;
    const int w    = tid >> 6, lane = tid & 63;
    const int lr   = lane & 15;
    const int lg   = lane >> 4;
    const int nb0  = blockIdx.x * 16;

    // fused sfeat: 240 output elements per block (625*240 = NNODES*15 exactly)
    if (tid < 240) {
        int gid = blockIdx.x*240 + tid;
        int n = gid/15, ii = gid%15;
        float v = (ii < 8) ? X[(size_t)n*8 + ii]
                           : X[((size_t)(ii-7)*NNODES + n)*8 + 7];
        out[(size_t)n*143 + 128 + ii] = v;
    }

    uint4 w1f[4][6], w2f[4][4];
    {
        const uint4* p1 = (const uint4*)W1f;
        #pragma unroll
        for (int nt = 0; nt < 4; ++nt)
            #pragma unroll
            for (int ks = 0; ks < 6; ++ks)
                w1f[nt][ks] = p1[((w*4 + nt)*6 + ks)*64 + lane];
        const uint4* p2 = (const uint4*)W2f;
        #pragma unroll
        for (int nt = 0; nt < 4; ++nt)
            #pragma unroll
            for (int ks = 0; ks < 4; ++ks)
                w2f[nt][ks] = p2[((w*4 + nt)*4 + ks)*64 + lane];
    }
    float b1v[4], b2v[4];
    #pragma unroll
    for (int nt = 0; nt < 4; ++nt) {
        b1v[nt] = bs1[nt*64 + w*16 + lr];
        b2v[nt] = bs2[nt*64 + w*16 + lr];
    }

    const int sn = tid >> 4, k0 = (tid & 15)*8;
    float ax[8], bx[8];
    if (k0 >= 64) {
        #pragma unroll
        for (int j = 0; j < 8; ++j) {
            int c = k0 - 64 + j;
            float mu  = sums2[c] * (1.0f/NT);
            float var = sums2[64 + c] * (1.0f/NT) - mu*mu;
            float a = rsqrtf(var + BNEPS) * g2[c];
            ax[j] = a; bx[j] = be2[c] - mu*a;
        }
    }

    for (int i = tid; i < 16*24; i += 256) {
        int n = i / 24, kk = 128 + (i % 24)*8;
        uint4 z; z.x = z.y = z.z = z.w = 0u;
        *(uint4*)&xb[n][kk] = z;
    }

    auto stage = [&](int step) {
        size_t row = (size_t)(step*NNODES + nb0 + sn);
        uint4 raw;
        if (k0 < 64) {
            raw = *(const uint4*)&xcat[row*64 + (k0 >> 1)];
        } else {
            raw = *(const uint4*)&y2[row*32 + ((k0 - 64) >> 1)];
            unsigned int um[4] = {raw.x, raw.y, raw.z, raw.w};
            #pragma unroll
            for (int m = 0; m < 4; ++m) {
                float v0 = fmaf(ax[2*m],   u2f(um[m] << 16),         bx[2*m]);
                float v1 = fmaf(ax[2*m+1], u2f(um[m] & 0xffff0000u), bx[2*m+1]);
                um[m] = pk2(v0, v1);
            }
            raw.x = um[0]; raw.y = um[1]; raw.z = um[2]; raw.w = um[3];
        }
        *(uint4*)&xb[sn][k0] = raw;
    };
    stage(0);
    float c1[4] = {0.f,0.f,0.f,0.f}, c2[4] = {0.f,0.f,0.f,0.f};

    for (int step = 0; step < 8; ++step) {
        __syncthreads();                    // B_a

        f32x4 acc[4];
        #pragma unroll
        for (int nt = 0; nt < 4; ++nt) { acc[nt][0]=0.f; acc[nt][1]=0.f; acc[nt][2]=0.f; acc[nt][3]=0.f; }
        #pragma unroll
        for (int ks = 0; ks < 6; ++ks) {
            bf16x8 a = *(const bf16x8*)&xb[lr][ks*32 + lg*8];
            #pragma unroll
            for (int nt = 0; nt < 4; ++nt) {
                union { uint4 u; bf16x8 v; } wb; wb.u = w1f[nt][ks];
                acc[nt] = __builtin_amdgcn_mfma_f32_16x16x32_bf16(a, wb.v, acc[nt], 0, 0, 0);
            }
        }
        __syncthreads();                    // B_b

        #pragma unroll
        for (int r = 0; r < 4; ++r) {
            float zi = acc[0][r] + b1v[0];
            float zf = acc[1][r] + b1v[1];
            float zg = acc[2][r] + b1v[2];
            float zo = acc[3][r] + b1v[3];
            float c  = fsig(zf)*c1[r] + fsig(zi)*ftanh(zg);
            c1[r] = c;
            float hv = fsig(zo)*ftanh(c);
            int node = lg*4 + r;
            xb[node][128 + w*16 + lr] = f2bu(hv);
            if (step == 7) out[(size_t)(nb0 + node)*143 + w*16 + lr] = hv;
        }
        if (step < 7) stage(step + 1);
        __syncthreads();                    // B_c

        int rb = 192 + 64*((step+1)&1);
        int wb2 = 192 + 64*(step&1);
        #pragma unroll
        for (int nt = 0; nt < 4; ++nt) { acc[nt][0]=0.f; acc[nt][1]=0.f; acc[nt][2]=0.f; acc[nt][3]=0.f; }
        #pragma unroll
        for (int ks = 0; ks < 2; ++ks) {
            bf16x8 a = *(const bf16x8*)&xb[lr][128 + ks*32 + lg*8];
            #pragma unroll
            for (int nt = 0; nt < 4; ++nt) {
                union { uint4 u; bf16x8 v; } wbv; wbv.u = w2f[nt][ks];
                acc[nt] = __builtin_amdgcn_mfma_f32_16x16x32_bf16(a, wbv.v, acc[nt], 0, 0, 0);
            }
        }
        #pragma unroll
        for (int ks = 0; ks < 2; ++ks) {
            bf16x8 a = *(const bf16x8*)&xb[lr][rb + ks*32 + lg*8];
            #pragma unroll
            for (int nt = 0; nt < 4; ++nt) {
                union { uint4 u; bf16x8 v; } wbv; wbv.u = w2f[nt][2+ks];
                acc[nt] = __builtin_amdgcn_mfma_f32_16x16x32_bf16(a, wbv.v, acc[nt], 0, 0, 0);
            }
        }
        #pragma unroll
        for (int r = 0; r < 4; ++r) {
            float zi = acc[0][r] + b2v[0];
            float zf = acc[1][r] + b2v[1];
            float zg = acc[2][r] + b2v[2];
            float zo = acc[3][r] + b2v[3];
            float c  = fsig(zf)*c2[r] + fsig(zi)*ftanh(zg);
            c2[r] = c;
            float hv = fsig(zo)*ftanh(c);
            int node = lg*4 + r;
            xb[node][wb2 + w*16 + lr] = f2bu(hv);
            if (step == 7) out[(size_t)(nb0 + node)*143 + 64 + w*16 + lr] = hv;
        }
    }
}

extern "C" void kernel_launch(void* const* d_in, const int* in_sizes, int n_in,
                              void* d_out, int out_size, void* d_ws, size_t ws_size,
                              hipStream_t stream)
{
    (void)in_sizes; (void)n_in; (void)out_size; (void)ws_size;
    const float* X    = (const float*)d_in[0];
    const int*   ei   = (const int*)d_in[1];
    const float* ew   = (const float*)d_in[2];
    const float* w1   = (const float*)d_in[3];
    const float* b1   = (const float*)d_in[4];
    const float* w2   = (const float*)d_in[5];
    const float* b2   = (const float*)d_in[6];
    const float* g1   = (const float*)d_in[7];
    const float* be1  = (const float*)d_in[8];
    const float* g2   = (const float*)d_in[9];
    const float* be2  = (const float*)d_in[10];
    const float* wih1 = (const float*)d_in[11];
    const float* whh1 = (const float*)d_in[12];
    const float* bih1 = (const float*)d_in[13];
    const float* bhh1 = (const float*)d_in[14];
    const float* wih2 = (const float*)d_in[15];
    const float* whh2 = (const float*)d_in[16];
    const float* bih2 = (const float*)d_in[17];
    const float* bhh2 = (const float*)d_in[18];
    float* out = (float*)d_out;
    float* ws  = (float*)d_ws;

    const int* src = ei;
    const int* dst = ei + NE;

    // workspace layout (word offsets)
    float* sums      = ws;                                //  256 [zeroed]
    float* dinv      = ws + 256;                          //  NT
    int*   rowptr    = (int*)(ws + 80256);                //  NT+1 (pad 4)
    int*   binTotal  = (int*)(ws + 160260);               //  625 (pad 640)
    int*   bucketbase= (int*)(ws + 160900);               //  626 (pad 640)
    int*   histmat   = (int*)(ws + 161540);               //  256*640
    int*   offmatT   = (int*)(ws + 325380);               //  625*256
    unsigned char* urank = (unsigned char*)(ws + 485380); //  NE bytes
    uint2* esort     = (uint2*)(ws + 805384);             //  NE*2 w
    unsigned int* x8 = (unsigned int*)(ws + 805384);      //  NT*16 w (alias: esort dead by then)
    unsigned int* y2 = (unsigned int*)(ws + 805384);      //  NT*32 w (alias: x8 dead by then)
    unsigned int* epack = (unsigned int*)(ws + 3365384);  //  NE w
    unsigned int* Xb = (unsigned int*)(ws + 4645384);     //  NT*4
    unsigned int* y1 = (unsigned int*)(ws + 5605384);     //  NT*32
    unsigned int* xcat = (unsigned int*)(ws + 8165384);   //  NT*64
    unsigned int* W1f  = (unsigned int*)(ws + 13285384);  //  24576
    unsigned int* W2f  = W1f + 24576;                     //  16384
    float* bs1 = (float*)(W2f + 16384);                   //  256
    float* bs2 = bs1 + 256;                               //  256
    unsigned int* W2g  = (unsigned int*)(bs2 + 256);      //  2048
    unsigned int* W1g  = W2g + 2048;                      //  1024

    hipMemsetAsync(ws, 0, 256 * 4, stream);

    // fused weight-prep + coarse histogram + xconv
    prepA1_kernel<<<430, 256, 0, stream>>>(dst, X, Xb, histmat,
                                           wih1,whh1,bih1,bhh1,
                                           wih2,whh2,bih2,bhh2,
                                           w1, w2,
                                           W1f,W2f,bs1,bs2,W2g,W1g);
    sortA2a_kernel<<<NBKT, 256, 0, stream>>>(histmat, offmatT, binTotal);
    sortA2b_kernel<<<1, 1024, 0, stream>>>(binTotal, bucketbase, rowptr);
    sortA3_kernel<<<256, 256, 0, stream>>>(src, dst, ew, offmatT, bucketbase, esort);
    sortB1_kernel<<<NBKT, 256, 0, stream>>>(bucketbase, esort, urank, rowptr, dinv);
    // B2 + layer-1 gather + layer-1 MFMA GEMM fused
    sortB2g8m_kernel<<<NBKT, 256, 0, stream>>>(bucketbase, esort, urank, rowptr, dinv,
                                               epack, (const uint4*)Xb, W1g, b1,
                                               (unsigned short*)y1, sums);

    // BN apply -> bf16 x1 (xcat[0:32]) + fp8 gather table x8
    xbn8_kernel<<<(NT*16+255)/256, 256, 0, stream>>>(y1, sums, g1, be1, xcat, x8);

    // GCN layer 2: fp8 gather (dual-dst MLP), MFMA GEMM (BN2 fused into LSTM)
    gather64_kernel<<<2048, 256, 0, stream>>>(rowptr, epack, x8, dinv, xcat);
    gemm64relu_kernel<<<320, 256, 0, stream>>>(xcat, W2g, b2, (unsigned short*)y2, sums + 128);

    // fused MFMA LSTM + skip features
    lstm_mfma_kernel<<<NNODES/16, 256, 0, stream>>>(xcat, y2, sums + 128, g2, be2,
                                                    W1f, W2f, bs1, bs2, X, out);
}